// Round 9
// baseline (926.503 us; speedup 1.0000x reference)
//
#include <hip/hip_runtime.h>
#include <math.h>

#define NU      256
#define NLAYERS 6
#define NBATCH  32768
#define NDIN    784
#define NDOUT   10
#define NUSQ    65536

typedef unsigned short u16;
typedef __attribute__((ext_vector_type(8))) short s16x8;
typedef __attribute__((ext_vector_type(4))) float f32x4;

// bf16 helpers (RNE)
__device__ __forceinline__ u16 f2bf(float x) {
    union { float f; unsigned u; } a; a.f = x;
    const unsigned r = a.u + 0x7fffu + ((a.u >> 16) & 1u);
    return (u16)(r >> 16);
}
__device__ __forceinline__ float bf2f(u16 h) {
    union { unsigned u; float f; } a; a.u = ((unsigned)h) << 16; return a.f;
}

// async global->LDS, 16 B per lane (m97 pattern; LDS dest = wave base + lane*16)
__device__ __forceinline__ void gl_lds16(const u16* g, u16* l) {
    __builtin_amdgcn_global_load_lds(
        (const __attribute__((address_space(1))) void*)g,
        (__attribute__((address_space(3))) void*)l, 16, 0, 0);
}

// uniform-lane float readlane (lane index must be wave-uniform)
__device__ __forceinline__ float rlf(float v, int lane) {
    return __int_as_float(__builtin_amdgcn_readlane(__float_as_int(v), lane));
}

// packed argmax key: |v| bits (top 24) | row (8 bits). unsigned-max == argmax.
__device__ __forceinline__ unsigned pkey(float v, int row) {
    return (__float_as_uint(fabsf(v)) & 0xFFFFFF00u) | (unsigned)row;
}

// wave64 unsigned-max reduce, pure VALU via DPP (no LDS pipe).
// row_shr 1/2/4/8 + row_bcast15 + row_bcast31. Result valid in lane 63.
__device__ __forceinline__ unsigned dpp_umax64_lane63(unsigned key) {
    unsigned t;
    t = (unsigned)__builtin_amdgcn_update_dpp(0, (int)key, 0x111, 0xf, 0xf, false); // row_shr:1
    key = key > t ? key : t;
    t = (unsigned)__builtin_amdgcn_update_dpp(0, (int)key, 0x112, 0xf, 0xf, false); // row_shr:2
    key = key > t ? key : t;
    t = (unsigned)__builtin_amdgcn_update_dpp(0, (int)key, 0x114, 0xf, 0xf, false); // row_shr:4
    key = key > t ? key : t;
    t = (unsigned)__builtin_amdgcn_update_dpp(0, (int)key, 0x118, 0xf, 0xf, false); // row_shr:8
    key = key > t ? key : t;
    t = (unsigned)__builtin_amdgcn_update_dpp(0, (int)key, 0x142, 0xf, 0xf, false); // row_bcast:15
    key = key > t ? key : t;
    t = (unsigned)__builtin_amdgcn_update_dpp(0, (int)key, 0x143, 0xf, 0xf, false); // row_bcast:31
    key = key > t ? key : t;
    return key;
}

// 32-way static-index dispatch over a wave-uniform column index.
#define COL_CASES(BODY) \
    case 0:  BODY(0);  break; case 1:  BODY(1);  break; \
    case 2:  BODY(2);  break; case 3:  BODY(3);  break; \
    case 4:  BODY(4);  break; case 5:  BODY(5);  break; \
    case 6:  BODY(6);  break; case 7:  BODY(7);  break; \
    case 8:  BODY(8);  break; case 9:  BODY(9);  break; \
    case 10: BODY(10); break; case 11: BODY(11); break; \
    case 12: BODY(12); break; case 13: BODY(13); break; \
    case 14: BODY(14); break; case 15: BODY(15); break; \
    case 16: BODY(16); break; case 17: BODY(17); break; \
    case 18: BODY(18); break; case 19: BODY(19); break; \
    case 20: BODY(20); break; case 21: BODY(21); break; \
    case 22: BODY(22); break; case 23: BODY(23); break; \
    case 24: BODY(24); break; case 25: BODY(25); break; \
    case 26: BODY(26); break; case 27: BODY(27); break; \
    case 28: BODY(28); break; case 29: BODY(29); break; \
    case 30: BODY(30); break; case 31: BODY(31); break;

// ---------------------------------------------------------------------------
// Fused first kernel: blocks 0..5 = GJ inversion (r5-proven: DPP argmax +
// readlane broadcast, no per-step DS traffic); blocks 6..517 = in_gemm
// (r0-proven fp32 body, threads>=256 exit).  BYTE-IDENTICAL to rounds 5/6.
// ---------------------------------------------------------------------------
__global__ __launch_bounds__(512, 2) void fused_inv_ingemm(
    const float* __restrict__ B0, const float* __restrict__ qg,
    u16* __restrict__ wnnh, u16* __restrict__ wnnl,
    u16* __restrict__ wnth, u16* __restrict__ wntl,
    float* __restrict__ bq,
    const float* __restrict__ X, const float* __restrict__ Win,
    const float* __restrict__ bin,
    u16* __restrict__ V0h, u16* __restrict__ V0l,
    u16* __restrict__ V1h, u16* __restrict__ V1l)
{
    // ---- invert LDS ----
    __shared__ __align__(16) float colv[2][256];
    __shared__ int   s_p[2];
    __shared__ float s_pv[2];
    __shared__ int   pivrow[256];
    __shared__ int   ilogrow[256];
    __shared__ float qs[256];
    __shared__ float part[8][256];
    // ---- in_gemm LDS ----
    __shared__ __align__(16) float As[16][128];
    __shared__ __align__(16) float Bs[16][128];

    const int tid = threadIdx.x;

    if (blockIdx.x < NLAYERS) {
        // =================== inversion path ===================
        const int layer = blockIdx.x;
        const int ct = tid & 63;     // lane: owns rows ct*4 .. ct*4+3
        const int wv = tid >> 6;     // wave: owns cols wv*32 .. wv*32+31

        float a[32][4];
        const float* Ablk = B0 + (size_t)layer * NU * NU;
#pragma unroll
        for (int j = 0; j < 4; ++j) {
            const float* rp = Ablk + (size_t)(ct*4 + j)*NU + wv*32;
#pragma unroll
            for (int i = 0; i < 32; i += 4) {
                const float4 v = *(const float4*)(rp + i);
                a[i+0][j] = v.x; a[i+1][j] = v.y; a[i+2][j] = v.z; a[i+3][j] = v.w;
            }
        }

        int used = 0;

        for (int k = 0; k < 256; ++k) {
            const int wvk = k >> 5, ikk = k & 31, buf = k & 1;

            if (wv == wvk) {
                float c0, c1, c2, c3;
#define EXT(I) { c0 = a[I][0]; c1 = a[I][1]; c2 = a[I][2]; c3 = a[I][3]; }
                switch (ikk) { COL_CASES(EXT) }
#undef EXT
                // packed-key argmax over unused rows, pure-VALU DPP reduce
                unsigned key = (used & 1) ? 0u : pkey(c0, ct*4 + 0);
                unsigned q1  = (used & 2) ? 0u : pkey(c1, ct*4 + 1); key = key > q1 ? key : q1;
                unsigned q2  = (used & 4) ? 0u : pkey(c2, ct*4 + 2); key = key > q2 ? key : q2;
                unsigned q3  = (used & 8) ? 0u : pkey(c3, ct*4 + 3); key = key > q3 ? key : q3;
                key = dpp_umax64_lane63(key);
                const int pn = __builtin_amdgcn_readlane((int)key, 63) & 255;
                float bv;
                switch (pn & 3) {
                    case 0: bv = rlf(c0, pn >> 2); break;
                    case 1: bv = rlf(c1, pn >> 2); break;
                    case 2: bv = rlf(c2, pn >> 2); break;
                    default: bv = rlf(c3, pn >> 2); break;
                }
                float4 cw; cw.x = c0; cw.y = c1; cw.z = c2; cw.w = c3;
                *(float4*)(&colv[buf][ct*4]) = cw;
                if (ct == 0) {
                    s_p[buf] = pn;
                    s_pv[buf] = 1.0f / bv;
                    pivrow[k] = pn;
                }
            }
            __syncthreads();

            const int   p      = __builtin_amdgcn_readfirstlane(s_p[buf]);
            const float pivinv = s_pv[buf];
            const int ctp = p >> 2, jp = p & 3;

            const float4 dv = *(const float4*)(&colv[buf][ct*4]);

            // pivot-row broadcast via v_readlane (VALU pipe; no ds_bpermute)
            float prw[32];
#define BRD(J) { _Pragma("unroll") for (int i = 0; i < 32; ++i) \
                    prw[i] = rlf(a[i][J], ctp) * pivinv; }
            switch (jp) {
                case 0: BRD(0) break; case 1: BRD(1) break;
                case 2: BRD(2) break; default: BRD(3) break;
            }
#undef BRD

            if (wv == wvk) {   // column-k special case ONLY in the owning wave
#define ZCOL(I) { prw[I] = pivinv; a[I][0] = 0.0f; a[I][1] = 0.0f; a[I][2] = 0.0f; a[I][3] = 0.0f; }
                switch (ikk) { COL_CASES(ZCOL) }
#undef ZCOL
            }

            const float d0 = -dv.x, d1 = -dv.y, d2 = -dv.z, d3 = -dv.w;
#pragma unroll
            for (int i = 0; i < 32; ++i) {
                const float pw = prw[i];
                a[i][0] = fmaf(d0, pw, a[i][0]);
                a[i][1] = fmaf(d1, pw, a[i][1]);
                a[i][2] = fmaf(d2, pw, a[i][2]);
                a[i][3] = fmaf(d3, pw, a[i][3]);
            }

            const bool mine = (ct == ctp);
#define OWR(J) { _Pragma("unroll") for (int i = 0; i < 32; ++i) a[i][J] = mine ? prw[i] : a[i][J]; }
            switch (jp) {
                case 0: OWR(0) break; case 1: OWR(1) break;
                case 2: OWR(2) break; default: OWR(3) break;
            }
#undef OWR
            if (mine) used |= (1 << jp);
        }
        __syncthreads();

        // stored a[i][j] = M[r][c], r = ilog[ct*4+j], c = pivrow[wv*32+i]
        if (tid < 256) { ilogrow[pivrow[tid]] = tid; qs[tid] = qg[(size_t)layer*NU + tid]; }
        __syncthreads();

        // ---- bq = M q ----
        {
            float s0=0.f, s1=0.f, s2=0.f, s3=0.f;
#pragma unroll
            for (int i = 0; i < 32; ++i) {
                const float qq = qs[pivrow[wv*32 + i]];
                s0 = fmaf(a[i][0], qq, s0);
                s1 = fmaf(a[i][1], qq, s1);
                s2 = fmaf(a[i][2], qq, s2);
                s3 = fmaf(a[i][3], qq, s3);
            }
            part[wv][ct*4+0] = s0; part[wv][ct*4+1] = s1;
            part[wv][ct*4+2] = s2; part[wv][ct*4+3] = s3;
        }
        __syncthreads();
        if (tid < 256) {
            float s = 0.f;
#pragma unroll
            for (int w2 = 0; w2 < 8; ++w2) s += part[w2][tid];
            bq[(size_t)layer*NU + ilogrow[tid]] = s;
        }

        // ---- split-bf16 W planes ----
        u16* nh = wnnh + (size_t)layer*NUSQ; u16* nl = wnnl + (size_t)layer*NUSQ;
        u16* th = wnth + (size_t)layer*NUSQ; u16* tl = wntl + (size_t)layer*NUSQ;
#pragma unroll
        for (int j = 0; j < 4; ++j) {
            const int r = ilogrow[ct*4 + j];
#pragma unroll
            for (int i = 0; i < 32; ++i) {
                const int c = pivrow[wv*32 + i];
                const float v = a[i][j];
                const u16 h  = f2bf(v);
                const u16 lo = f2bf(v - bf2f(h));
                th[(size_t)r*NU + c] = h;  tl[(size_t)r*NU + c] = lo;  // wnt[n][k]=M[n][k]
                nh[(size_t)c*NU + r] = h;  nl[(size_t)c*NU + r] = lo;  // wnn[n][k]=M[k][n]
            }
        }
        return;
    }

    // =================== in_gemm path (256 active threads) ===================
    if (tid >= 256) return;   // exited waves free their slots; HW barrier counts rest

    const int bid = blockIdx.x - NLAYERS;
    const int m0 = (bid & 255) * 128;
    const int n0 = (bid >> 8) * 128;
    const int t  = tid;
    const int tx = t & 15, ty = t >> 4;
    const int K = NDIN;

    float acc[8][8];
#pragma unroll
    for (int i = 0; i < 8; ++i)
#pragma unroll
        for (int j = 0; j < 8; ++j) acc[i][j] = 0.0f;

    const int am = t >> 1;
    const int ak = (t & 1) * 8;
    const int bk = t >> 4;
    const int bn = (t & 15) * 8;

    for (int k0 = 0; k0 < K; k0 += 16) {
        const float* Ap = X + (size_t)(m0 + am)*K + (k0 + ak);
        const float4 a0 = *(const float4*)(Ap);
        const float4 a1 = *(const float4*)(Ap + 4);
        As[ak+0][am] = a0.x; As[ak+1][am] = a0.y; As[ak+2][am] = a0.z; As[ak+3][am] = a0.w;
        As[ak+4][am] = a1.x; As[ak+5][am] = a1.y; As[ak+6][am] = a1.z; As[ak+7][am] = a1.w;
        const float* Bp = Win + (size_t)(k0 + bk)*NU + (n0 + bn);
        const float4 b0 = *(const float4*)(Bp);
        const float4 b1 = *(const float4*)(Bp + 4);
        *(float4*)(&Bs[bk][bn])   = b0;
        *(float4*)(&Bs[bk][bn+4]) = b1;
        __syncthreads();
#pragma unroll
        for (int kk = 0; kk < 16; ++kk) {
            float af[8], bf[8];
            *(float4*)(af)   = *(const float4*)(&As[kk][ty*8]);
            *(float4*)(af+4) = *(const float4*)(&As[kk][ty*8+4]);
            *(float4*)(bf)   = *(const float4*)(&Bs[kk][tx*8]);
            *(float4*)(bf+4) = *(const float4*)(&Bs[kk][tx*8+4]);
#pragma unroll
            for (int i = 0; i < 8; ++i)
#pragma unroll
                for (int j = 0; j < 8; ++j)
                    acc[i][j] = fmaf(af[i], bf[j], acc[i][j]);
        }
        __syncthreads();
    }

#pragma unroll
    for (int i = 0; i < 8; ++i) {
        const size_t row = m0 + ty*8 + i;
        s16x8 vh, vl, th2, tl2;
#pragma unroll
        for (int j = 0; j < 8; ++j) {
            const float v = acc[i][j] + bin[n0 + tx*8 + j];
            const u16 h  = f2bf(v);
            vh[j] = (short)h; vl[j] = (short)f2bf(v - bf2f(h));
            const float tv = tanhf(v);
            const u16 h2 = f2bf(tv);
            th2[j] = (short)h2; tl2[j] = (short)f2bf(tv - bf2f(h2));
        }
        const size_t o = row*NU + n0 + tx*8;
        *(s16x8*)&V0h[o] = vh; *(s16x8*)&V0l[o] = vl;
        *(s16x8*)&V1h[o] = th2; *(s16x8*)&V1l[o] = tl2;
    }
}

// ---------------------------------------------------------------------------
// Split-bf16 MFMA GEMM v2b: r6's passing 64x256 full-N tile kernel with ONE
// change: B fragments load directly global->VGPR (B is 256 KB, L2-resident
// for all 512 blocks; address (w*64+nt*16+l15)*NU + k0 + qd*8 is exactly the
// element r6 read from its staged LDS copy, 16 B aligned). This removes 8 of
// the 10 global_load_lds from each K-iter's vmcnt(0) barrier-drain path and
// drops LDS 40 KB -> 8 KB per block (occupancy can exceed 2 blocks/CU,
// strengthening cross-block latency overlap). A staging, barriers, fragment
// maps, epilogue: byte-identical to r6.
// ---------------------------------------------------------------------------
__global__ __launch_bounds__(256, 2) void gemm_mfma(
    const u16* __restrict__ Ah, const u16* __restrict__ Al,
    const u16* __restrict__ Bh, const u16* __restrict__ Bl,
    u16* __restrict__ Ch, u16* __restrict__ Cl,
    const float* __restrict__ bias, const float alpha)
{
    __shared__ __align__(16) u16 lAh[64*32], lAl[64*32];
    const int t    = threadIdx.x;
    const int lane = t & 63;
    const int w    = t >> 6;           // wave 0..3 owns cols w*64 .. w*64+63
    const int qd = lane >> 4, l15 = lane & 15;
    const int m0 = blockIdx.x * 64;

    const int srow = t >> 2;           // 0..63
    const int skc  = (t & 3) * 8;      // element offset 0,8,16,24

    f32x4 acc[4][4];
    const f32x4 z = {0.f, 0.f, 0.f, 0.f};
#pragma unroll
    for (int i = 0; i < 4; ++i)
#pragma unroll
        for (int j = 0; j < 4; ++j) acc[i][j] = z;

    for (int k0 = 0; k0 < NU; k0 += 32) {
        // A planes: 64 rows x 32 k = 4 KB each -> one gl_lds call per plane
        {
            const size_t ga = (size_t)(m0 + srow)*NU + k0 + skc;
            const int lo = srow*32 + skc;          // byte 16*t
            gl_lds16(Ah + ga, &lAh[lo]);
            gl_lds16(Al + ga, &lAl[lo]);
        }

        // B fragments: direct global->reg (L2-hot, no LDS round-trip)
        s16x8 bh[4], bl[4];
#pragma unroll
        for (int nt = 0; nt < 4; ++nt) {
            const size_t gb = (size_t)(w*64 + nt*16 + l15)*NU + k0 + qd*8;
            bh[nt] = *(const s16x8*)&Bh[gb];
            bl[nt] = *(const s16x8*)&Bl[gb];
        }

        __syncthreads();   // drains A stage (and B loads) -> LDS valid

        s16x8 ah[4], al[4];
#pragma unroll
        for (int mt = 0; mt < 4; ++mt) {
            const int off = (mt*16 + l15)*32 + qd*8;
            ah[mt] = *(const s16x8*)&lAh[off];
            al[mt] = *(const s16x8*)&lAl[off];
        }

#pragma unroll
        for (int mt = 0; mt < 4; ++mt)
#pragma unroll
            for (int nt = 0; nt < 4; ++nt) {
                acc[mt][nt] = __builtin_amdgcn_mfma_f32_16x16x32_bf16(ah[mt], bh[nt], acc[mt][nt], 0, 0, 0);
                acc[mt][nt] = __builtin_amdgcn_mfma_f32_16x16x32_bf16(ah[mt], bl[nt], acc[mt][nt], 0, 0, 0);
                acc[mt][nt] = __builtin_amdgcn_mfma_f32_16x16x32_bf16(al[mt], bh[nt], acc[mt][nt], 0, 0, 0);
            }
        __syncthreads();   // protect LDS buffer reuse next iter
    }

#pragma unroll
    for (int mt = 0; mt < 4; ++mt) {
#pragma unroll
        for (int nt = 0; nt < 4; ++nt) {
            const int col = w*64 + nt*16 + l15;
            const float bb = bias ? bias[col] : 0.0f;
#pragma unroll
            for (int r = 0; r < 4; ++r) {
                const int row = m0 + mt*16 + qd*4 + r;
                const float v = alpha*acc[mt][nt][r] + bb;
                const u16 h  = f2bf(v);
                const u16 lo = f2bf(v - bf2f(h));
                const size_t o = (size_t)row*NU + col;
                Ch[o] = h; Cl[o] = lo;
            }
        }
    }
}

// ---------------------------------------------------------------------------
// out = V0 @ W_out + b_out, N=10. One wave per batch row; V0 from planes.
// ---------------------------------------------------------------------------
__global__ __launch_bounds__(256) void out_gemm(
    const u16* __restrict__ V0h, const u16* __restrict__ V0l,
    const float* __restrict__ Wout,
    const float* __restrict__ bout, float* __restrict__ out)
{
    __shared__ float Ws[NU*NDOUT];
    const int t = threadIdx.x;
    for (int i = t; i < NU*NDOUT; i += 256) Ws[i] = Wout[i];
    __syncthreads();
    const int lane = t & 63;
    const int wv = t >> 6;
    const int row = blockIdx.x*4 + wv;
    float acc[NDOUT];
#pragma unroll
    for (int j = 0; j < NDOUT; ++j) acc[j] = 0.0f;
#pragma unroll
    for (int s = 0; s < 4; ++s) {
        const int k = lane + 64*s;
        const size_t o = (size_t)row*NU + k;
        const float v = bf2f(V0h[o]) + bf2f(V0l[o]);
#pragma unroll
        for (int j = 0; j < NDOUT; ++j) acc[j] = fmaf(v, Ws[k*NDOUT + j], acc[j]);
    }
#pragma unroll
    for (int off = 32; off > 0; off >>= 1) {
#pragma unroll
        for (int j = 0; j < NDOUT; ++j) acc[j] += __shfl_down(acc[j], off);
    }
    if (lane == 0) {
#pragma unroll
        for (int j = 0; j < NDOUT; ++j) out[(size_t)row*NDOUT + j] = acc[j] + bout[j];
    }
}

extern "C" void kernel_launch(void* const* d_in, const int* in_sizes, int n_in,
                              void* d_out, int out_size, void* d_ws, size_t ws_size,
                              hipStream_t stream)
{
    const float* x    = (const float*)d_in[0];
    const float* Win  = (const float*)d_in[1];
    const float* bin  = (const float*)d_in[2];
    const float* B0   = (const float*)d_in[3];
    const float* q    = (const float*)d_in[4];
    const float* Wout = (const float*)d_in[5];
    const float* bout = (const float*)d_in[6];
    float* out = (float*)d_out;

    // workspace carve (~104 MB)
    u16* wnnh = (u16*)d_ws;
    u16* wnnl = wnnh + (size_t)NLAYERS*NUSQ;
    u16* wnth = wnnl + (size_t)NLAYERS*NUSQ;
    u16* wntl = wnth + (size_t)NLAYERS*NUSQ;
    float* bq = (float*)(wntl + (size_t)NLAYERS*NUSQ);
    u16* pl   = (u16*)(bq + NLAYERS*NU);
    const size_t PSZ = (size_t)NBATCH*NU;
    u16* sAh = pl;           u16* sAl = sAh + PSZ;   // slot A (V0)
    u16* sBh = sAl + PSZ;    u16* sBl = sBh + PSZ;   // slot B (V1)
    u16* sCh = sBl + PSZ;    u16* sCl = sCh + PSZ;   // slot C (free)

    // fused: 6 invert blocks + 512 in_gemm blocks, concurrent
    fused_inv_ingemm<<<NLAYERS + 512, 512, 0, stream>>>(
        B0, q, wnnh, wnnl, wnth, wntl, bq,
        x, Win, bin, sAh, sAl, sBh, sBl);

    const dim3 ggrid(NBATCH/64);   // 512 blocks, full-N tiles

    u16 *v0h = sAh, *v0l = sAl, *v1h = sBh, *v1l = sBl, *frh = sCh, *frl = sCl;
    for (int l = 0; l < NLAYERS; ++l) {
        const size_t wo = (size_t)l*NUSQ;
        // newV0 = -V1 @ M
        gemm_mfma<<<ggrid, 256, 0, stream>>>(v1h, v1l, wnnh + wo, wnnl + wo,
                                             frh, frl, nullptr, -1.0f);
        // newV1 = V0 @ M^T + (Mq)^T
        gemm_mfma<<<ggrid, 256, 0, stream>>>(v0h, v0l, wnth + wo, wntl + wo,
                                             v1h, v1l, bq + (size_t)l*NU, 1.0f);
        u16* t0 = v0h; u16* t1 = v0l;
        v0h = frh; v0l = frl; frh = t0; frl = t1;
    }
    out_gemm<<<NBATCH/4, 256, 0, stream>>>(v0h, v0l, Wout, bout, out);
}

// Round 10
// 875.885 us; speedup vs baseline: 1.0578x; 1.0578x over previous
//
#include <hip/hip_runtime.h>
#include <math.h>

#define NU      256
#define NLAYERS 6
#define NBATCH  32768
#define NDIN    784
#define NDOUT   10
#define NUSQ    65536

typedef unsigned short u16;
typedef __attribute__((ext_vector_type(8))) short s16x8;
typedef __attribute__((ext_vector_type(4))) float f32x4;
typedef __attribute__((ext_vector_type(2))) float f32x2;

// bf16 helpers (RNE)
__device__ __forceinline__ u16 f2bf(float x) {
    union { float f; unsigned u; } a; a.f = x;
    const unsigned r = a.u + 0x7fffu + ((a.u >> 16) & 1u);
    return (u16)(r >> 16);
}
__device__ __forceinline__ float bf2f(u16 h) {
    union { unsigned u; float f; } a; a.u = ((unsigned)h) << 16; return a.f;
}

// async global->LDS, 16 B per lane (m97 pattern; LDS dest = wave base + lane*16)
__device__ __forceinline__ void gl_lds16(const u16* g, u16* l) {
    __builtin_amdgcn_global_load_lds(
        (const __attribute__((address_space(1))) void*)g,
        (__attribute__((address_space(3))) void*)l, 16, 0, 0);
}

// uniform-lane float readlane (lane index must be wave-uniform)
__device__ __forceinline__ float rlf(float v, int lane) {
    return __int_as_float(__builtin_amdgcn_readlane(__float_as_int(v), lane));
}

// packed argmax key: |v| bits (top 24) | row (8 bits). unsigned-max == argmax.
__device__ __forceinline__ unsigned pkey(float v, int row) {
    return (__float_as_uint(fabsf(v)) & 0xFFFFFF00u) | (unsigned)row;
}

// wave64 unsigned-max reduce, pure VALU via DPP (no LDS pipe).
// row_shr 1/2/4/8 + row_bcast15 + row_bcast31. Result valid in lane 63.
__device__ __forceinline__ unsigned dpp_umax64_lane63(unsigned key) {
    unsigned t;
    t = (unsigned)__builtin_amdgcn_update_dpp(0, (int)key, 0x111, 0xf, 0xf, false); // row_shr:1
    key = key > t ? key : t;
    t = (unsigned)__builtin_amdgcn_update_dpp(0, (int)key, 0x112, 0xf, 0xf, false); // row_shr:2
    key = key > t ? key : t;
    t = (unsigned)__builtin_amdgcn_update_dpp(0, (int)key, 0x114, 0xf, 0xf, false); // row_shr:4
    key = key > t ? key : t;
    t = (unsigned)__builtin_amdgcn_update_dpp(0, (int)key, 0x118, 0xf, 0xf, false); // row_shr:8
    key = key > t ? key : t;
    t = (unsigned)__builtin_amdgcn_update_dpp(0, (int)key, 0x142, 0xf, 0xf, false); // row_bcast:15
    key = key > t ? key : t;
    t = (unsigned)__builtin_amdgcn_update_dpp(0, (int)key, 0x143, 0xf, 0xf, false); // row_bcast:31
    key = key > t ? key : t;
    return key;
}

// 32-way static-index dispatch over a wave-uniform column index.
#define COL_CASES(BODY) \
    case 0:  BODY(0);  break; case 1:  BODY(1);  break; \
    case 2:  BODY(2);  break; case 3:  BODY(3);  break; \
    case 4:  BODY(4);  break; case 5:  BODY(5);  break; \
    case 6:  BODY(6);  break; case 7:  BODY(7);  break; \
    case 8:  BODY(8);  break; case 9:  BODY(9);  break; \
    case 10: BODY(10); break; case 11: BODY(11); break; \
    case 12: BODY(12); break; case 13: BODY(13); break; \
    case 14: BODY(14); break; case 15: BODY(15); break; \
    case 16: BODY(16); break; case 17: BODY(17); break; \
    case 18: BODY(18); break; case 19: BODY(19); break; \
    case 20: BODY(20); break; case 21: BODY(21); break; \
    case 22: BODY(22); break; case 23: BODY(23); break; \
    case 24: BODY(24); break; case 25: BODY(25); break; \
    case 26: BODY(26); break; case 27: BODY(27); break; \
    case 28: BODY(28); break; case 29: BODY(29); break; \
    case 30: BODY(30); break; case 31: BODY(31); break;

// ---------------------------------------------------------------------------
// Fused first kernel: blocks 0..5 = GJ inversion (r5-proven: DPP argmax +
// readlane broadcast, no per-step DS traffic); blocks 6..517 = in_gemm
// (r0-proven fp32 body, threads>=256 exit).  BYTE-IDENTICAL to rounds 5/6/9.
// ---------------------------------------------------------------------------
__global__ __launch_bounds__(512, 2) void fused_inv_ingemm(
    const float* __restrict__ B0, const float* __restrict__ qg,
    u16* __restrict__ wnnh, u16* __restrict__ wnnl,
    u16* __restrict__ wnth, u16* __restrict__ wntl,
    float* __restrict__ bq,
    const float* __restrict__ X, const float* __restrict__ Win,
    const float* __restrict__ bin,
    u16* __restrict__ V0h, u16* __restrict__ V0l,
    u16* __restrict__ V1h, u16* __restrict__ V1l)
{
    // ---- invert LDS ----
    __shared__ __align__(16) float colv[2][256];
    __shared__ int   s_p[2];
    __shared__ float s_pv[2];
    __shared__ int   pivrow[256];
    __shared__ int   ilogrow[256];
    __shared__ float qs[256];
    __shared__ float part[8][256];
    // ---- in_gemm LDS ----
    __shared__ __align__(16) float As[16][128];
    __shared__ __align__(16) float Bs[16][128];

    const int tid = threadIdx.x;

    if (blockIdx.x < NLAYERS) {
        // =================== inversion path ===================
        const int layer = blockIdx.x;
        const int ct = tid & 63;     // lane: owns rows ct*4 .. ct*4+3
        const int wv = tid >> 6;     // wave: owns cols wv*32 .. wv*32+31

        float a[32][4];
        const float* Ablk = B0 + (size_t)layer * NU * NU;
#pragma unroll
        for (int j = 0; j < 4; ++j) {
            const float* rp = Ablk + (size_t)(ct*4 + j)*NU + wv*32;
#pragma unroll
            for (int i = 0; i < 32; i += 4) {
                const float4 v = *(const float4*)(rp + i);
                a[i+0][j] = v.x; a[i+1][j] = v.y; a[i+2][j] = v.z; a[i+3][j] = v.w;
            }
        }

        int used = 0;

        for (int k = 0; k < 256; ++k) {
            const int wvk = k >> 5, ikk = k & 31, buf = k & 1;

            if (wv == wvk) {
                float c0, c1, c2, c3;
#define EXT(I) { c0 = a[I][0]; c1 = a[I][1]; c2 = a[I][2]; c3 = a[I][3]; }
                switch (ikk) { COL_CASES(EXT) }
#undef EXT
                // packed-key argmax over unused rows, pure-VALU DPP reduce
                unsigned key = (used & 1) ? 0u : pkey(c0, ct*4 + 0);
                unsigned q1  = (used & 2) ? 0u : pkey(c1, ct*4 + 1); key = key > q1 ? key : q1;
                unsigned q2  = (used & 4) ? 0u : pkey(c2, ct*4 + 2); key = key > q2 ? key : q2;
                unsigned q3  = (used & 8) ? 0u : pkey(c3, ct*4 + 3); key = key > q3 ? key : q3;
                key = dpp_umax64_lane63(key);
                const int pn = __builtin_amdgcn_readlane((int)key, 63) & 255;
                float bv;
                switch (pn & 3) {
                    case 0: bv = rlf(c0, pn >> 2); break;
                    case 1: bv = rlf(c1, pn >> 2); break;
                    case 2: bv = rlf(c2, pn >> 2); break;
                    default: bv = rlf(c3, pn >> 2); break;
                }
                float4 cw; cw.x = c0; cw.y = c1; cw.z = c2; cw.w = c3;
                *(float4*)(&colv[buf][ct*4]) = cw;
                if (ct == 0) {
                    s_p[buf] = pn;
                    s_pv[buf] = 1.0f / bv;
                    pivrow[k] = pn;
                }
            }
            __syncthreads();

            const int   p      = __builtin_amdgcn_readfirstlane(s_p[buf]);
            const float pivinv = s_pv[buf];
            const int ctp = p >> 2, jp = p & 3;

            const float4 dv = *(const float4*)(&colv[buf][ct*4]);

            // pivot-row broadcast via v_readlane (VALU pipe; no ds_bpermute)
            float prw[32];
#define BRD(J) { _Pragma("unroll") for (int i = 0; i < 32; ++i) \
                    prw[i] = rlf(a[i][J], ctp) * pivinv; }
            switch (jp) {
                case 0: BRD(0) break; case 1: BRD(1) break;
                case 2: BRD(2) break; default: BRD(3) break;
            }
#undef BRD

            if (wv == wvk) {   // column-k special case ONLY in the owning wave
#define ZCOL(I) { prw[I] = pivinv; a[I][0] = 0.0f; a[I][1] = 0.0f; a[I][2] = 0.0f; a[I][3] = 0.0f; }
                switch (ikk) { COL_CASES(ZCOL) }
#undef ZCOL
            }

            const float d0 = -dv.x, d1 = -dv.y, d2 = -dv.z, d3 = -dv.w;
#pragma unroll
            for (int i = 0; i < 32; ++i) {
                const float pw = prw[i];
                a[i][0] = fmaf(d0, pw, a[i][0]);
                a[i][1] = fmaf(d1, pw, a[i][1]);
                a[i][2] = fmaf(d2, pw, a[i][2]);
                a[i][3] = fmaf(d3, pw, a[i][3]);
            }

            const bool mine = (ct == ctp);
#define OWR(J) { _Pragma("unroll") for (int i = 0; i < 32; ++i) a[i][J] = mine ? prw[i] : a[i][J]; }
            switch (jp) {
                case 0: OWR(0) break; case 1: OWR(1) break;
                case 2: OWR(2) break; default: OWR(3) break;
            }
#undef OWR
            if (mine) used |= (1 << jp);
        }
        __syncthreads();

        // stored a[i][j] = M[r][c], r = ilog[ct*4+j], c = pivrow[wv*32+i]
        if (tid < 256) { ilogrow[pivrow[tid]] = tid; qs[tid] = qg[(size_t)layer*NU + tid]; }
        __syncthreads();

        // ---- bq = M q ----
        {
            float s0=0.f, s1=0.f, s2=0.f, s3=0.f;
#pragma unroll
            for (int i = 0; i < 32; ++i) {
                const float qq = qs[pivrow[wv*32 + i]];
                s0 = fmaf(a[i][0], qq, s0);
                s1 = fmaf(a[i][1], qq, s1);
                s2 = fmaf(a[i][2], qq, s2);
                s3 = fmaf(a[i][3], qq, s3);
            }
            part[wv][ct*4+0] = s0; part[wv][ct*4+1] = s1;
            part[wv][ct*4+2] = s2; part[wv][ct*4+3] = s3;
        }
        __syncthreads();
        if (tid < 256) {
            float s = 0.f;
#pragma unroll
            for (int w2 = 0; w2 < 8; ++w2) s += part[w2][tid];
            bq[(size_t)layer*NU + ilogrow[tid]] = s;
        }

        // ---- split-bf16 W planes ----
        u16* nh = wnnh + (size_t)layer*NUSQ; u16* nl = wnnl + (size_t)layer*NUSQ;
        u16* th = wnth + (size_t)layer*NUSQ; u16* tl = wntl + (size_t)layer*NUSQ;
#pragma unroll
        for (int j = 0; j < 4; ++j) {
            const int r = ilogrow[ct*4 + j];
#pragma unroll
            for (int i = 0; i < 32; ++i) {
                const int c = pivrow[wv*32 + i];
                const float v = a[i][j];
                const u16 h  = f2bf(v);
                const u16 lo = f2bf(v - bf2f(h));
                th[(size_t)r*NU + c] = h;  tl[(size_t)r*NU + c] = lo;  // wnt[n][k]=M[n][k]
                nh[(size_t)c*NU + r] = h;  nl[(size_t)c*NU + r] = lo;  // wnn[n][k]=M[k][n]
            }
        }
        return;
    }

    // =================== in_gemm path (256 active threads) ===================
    if (tid >= 256) return;   // exited waves free their slots; HW barrier counts rest

    const int bid = blockIdx.x - NLAYERS;
    const int m0 = (bid & 255) * 128;
    const int n0 = (bid >> 8) * 128;
    const int t  = tid;
    const int tx = t & 15, ty = t >> 4;
    const int K = NDIN;

    float acc[8][8];
#pragma unroll
    for (int i = 0; i < 8; ++i)
#pragma unroll
        for (int j = 0; j < 8; ++j) acc[i][j] = 0.0f;

    const int am = t >> 1;
    const int ak = (t & 1) * 8;
    const int bk = t >> 4;
    const int bn = (t & 15) * 8;

    for (int k0 = 0; k0 < K; k0 += 16) {
        const float* Ap = X + (size_t)(m0 + am)*K + (k0 + ak);
        const float4 a0 = *(const float4*)(Ap);
        const float4 a1 = *(const float4*)(Ap + 4);
        As[ak+0][am] = a0.x; As[ak+1][am] = a0.y; As[ak+2][am] = a0.z; As[ak+3][am] = a0.w;
        As[ak+4][am] = a1.x; As[ak+5][am] = a1.y; As[ak+6][am] = a1.z; As[ak+7][am] = a1.w;
        const float* Bp = Win + (size_t)(k0 + bk)*NU + (n0 + bn);
        const float4 b0 = *(const float4*)(Bp);
        const float4 b1 = *(const float4*)(Bp + 4);
        *(float4*)(&Bs[bk][bn])   = b0;
        *(float4*)(&Bs[bk][bn+4]) = b1;
        __syncthreads();
#pragma unroll
        for (int kk = 0; kk < 16; ++kk) {
            float af[8], bf[8];
            *(float4*)(af)   = *(const float4*)(&As[kk][ty*8]);
            *(float4*)(af+4) = *(const float4*)(&As[kk][ty*8+4]);
            *(float4*)(bf)   = *(const float4*)(&Bs[kk][tx*8]);
            *(float4*)(bf+4) = *(const float4*)(&Bs[kk][tx*8+4]);
#pragma unroll
            for (int i = 0; i < 8; ++i)
#pragma unroll
                for (int j = 0; j < 8; ++j)
                    acc[i][j] = fmaf(af[i], bf[j], acc[i][j]);
        }
        __syncthreads();
    }

#pragma unroll
    for (int i = 0; i < 8; ++i) {
        const size_t row = m0 + ty*8 + i;
        s16x8 vh, vl, th2, tl2;
#pragma unroll
        for (int j = 0; j < 8; ++j) {
            const float v = acc[i][j] + bin[n0 + tx*8 + j];
            const u16 h  = f2bf(v);
            vh[j] = (short)h; vl[j] = (short)f2bf(v - bf2f(h));
            const float tv = tanhf(v);
            const u16 h2 = f2bf(tv);
            th2[j] = (short)h2; tl2[j] = (short)f2bf(tv - bf2f(h2));
        }
        const size_t o = row*NU + n0 + tx*8;
        *(s16x8*)&V0h[o] = vh; *(s16x8*)&V0l[o] = vl;
        *(s16x8*)&V1h[o] = th2; *(s16x8*)&V1l[o] = tl2;
    }
}

// ---------------------------------------------------------------------------
// Split-bf16 MFMA GEMM (r5-proven structure): 128x128 tile, BK=32, 4 waves
// (2x2), wave = 64x64 = 4x4 MFMA 16x16x32, staging via global_load_lds
// width=16 (lane-contiguous), split product hh+hl+lh.
// NEW this round (only change): vectorized C writeback. Each wave repacks
// its 64x64 f32 acc tile through a private padded LDS zone (stride 66 f32:
// 2-way bank access on writes, 8B-aligned f32x2 reads) in two 32-row passes,
// then emits 16B s16x8 stores -- 8-lane groups write 128B fully-contiguous
// lines (was: 128 scalar 2B stores/thread at 32B granularity, ~2x HBM write
// amplification). Values bit-identical; no new barriers (zones wave-private).
// ---------------------------------------------------------------------------
__global__ __launch_bounds__(256, 2) void gemm_mfma(
    const u16* __restrict__ Ah, const u16* __restrict__ Al,
    const u16* __restrict__ Bh, const u16* __restrict__ Bl,
    u16* __restrict__ Ch, u16* __restrict__ Cl,
    const float* __restrict__ bias, const float alpha)
{
    __shared__ __align__(16) u16 lAh[128*32], lAl[128*32], lBh[128*32], lBl[128*32];
    __shared__ __align__(16) float fbuf[4*2112];   // 4 waves x [32 rows][66 f32]
    const int t    = threadIdx.x;
    const int lane = t & 63;
    const int w    = t >> 6;
    const int wr = w >> 1, wc = w & 1;
    const int qd = lane >> 4, l15 = lane & 15;
    const int m0 = blockIdx.x * 128, n0 = blockIdx.y * 128;

    const int srow = t >> 2;          // 0..63
    const int skc  = (t & 3) * 8;     // 0,8,16,24

    f32x4 acc[4][4];
    const f32x4 z = {0.f, 0.f, 0.f, 0.f};
#pragma unroll
    for (int i = 0; i < 4; ++i)
#pragma unroll
        for (int j = 0; j < 4; ++j) acc[i][j] = z;

    for (int k0 = 0; k0 < NU; k0 += 32) {
#pragma unroll
        for (int half = 0; half < 2; ++half) {
            const int rr = srow + half*64;
            const size_t ga = (size_t)(m0 + rr)*NU + k0 + skc;
            const size_t gb = (size_t)(n0 + rr)*NU + k0 + skc;
            const int lo = rr*32 + skc;
            gl_lds16(Ah + ga, &lAh[lo]);
            gl_lds16(Al + ga, &lAl[lo]);
            gl_lds16(Bh + gb, &lBh[lo]);
            gl_lds16(Bl + gb, &lBl[lo]);
        }
        __syncthreads();

        s16x8 ah[4], al[4], bh[4], bl[4];
#pragma unroll
        for (int mt = 0; mt < 4; ++mt) {
            const int off = (wr*64 + mt*16 + l15)*32 + qd*8;
            ah[mt] = *(const s16x8*)&lAh[off];
            al[mt] = *(const s16x8*)&lAl[off];
        }
#pragma unroll
        for (int nt = 0; nt < 4; ++nt) {
            const int off = (wc*64 + nt*16 + l15)*32 + qd*8;
            bh[nt] = *(const s16x8*)&lBh[off];
            bl[nt] = *(const s16x8*)&lBl[off];
        }
#pragma unroll
        for (int mt = 0; mt < 4; ++mt)
#pragma unroll
            for (int nt = 0; nt < 4; ++nt) {
                acc[mt][nt] = __builtin_amdgcn_mfma_f32_16x16x32_bf16(ah[mt], bh[nt], acc[mt][nt], 0, 0, 0);
                acc[mt][nt] = __builtin_amdgcn_mfma_f32_16x16x32_bf16(ah[mt], bl[nt], acc[mt][nt], 0, 0, 0);
                acc[mt][nt] = __builtin_amdgcn_mfma_f32_16x16x32_bf16(al[mt], bh[nt], acc[mt][nt], 0, 0, 0);
            }
        __syncthreads();
    }

    // ---- vectorized epilogue: per-wave LDS f32 repack, 2 passes of 32 rows ----
    float bb[4];
#pragma unroll
    for (int nt = 0; nt < 4; ++nt) {
        const int col = n0 + wc*64 + nt*16 + l15;
        bb[nt] = bias ? bias[col] : 0.0f;
    }
    float* zone = &fbuf[w*2112];
    const int s8 = lane >> 3;          // 0..7
    const int c8 = (lane & 7) * 8;     // 0,8,..,56 (col within wave tile)

#pragma unroll
    for (int p = 0; p < 2; ++p) {
        // write: acc (rows p*32..p*32+31 of wave tile) -> zone[row][col], stride 66
#pragma unroll
        for (int mt2 = 0; mt2 < 2; ++mt2) {
            const int mt = 2*p + mt2;
#pragma unroll
            for (int nt = 0; nt < 4; ++nt)
#pragma unroll
                for (int r = 0; r < 4; ++r)
                    zone[(mt2*16 + qd*4 + r)*66 + nt*16 + l15] =
                        alpha*acc[mt][nt][r] + bb[nt];
        }
        // read back row-major (same wave; compiler inserts lgkmcnt) + 16B stores
#pragma unroll
        for (int u = 0; u < 4; ++u) {
            const int rl = u*8 + s8;                   // 0..31
            const float* src = &zone[rl*66 + c8];
            float v8[8];
            *(f32x2*)(v8)   = *(const f32x2*)(src);
            *(f32x2*)(v8+2) = *(const f32x2*)(src+2);
            *(f32x2*)(v8+4) = *(const f32x2*)(src+4);
            *(f32x2*)(v8+6) = *(const f32x2*)(src+6);
            s16x8 vh, vl;
#pragma unroll
            for (int j = 0; j < 8; ++j) {
                const u16 h = f2bf(v8[j]);
                vh[j] = (short)h;
                vl[j] = (short)f2bf(v8[j] - bf2f(h));
            }
            const size_t o = (size_t)(m0 + wr*64 + p*32 + rl)*NU + (n0 + wc*64 + c8);
            *(s16x8*)&Ch[o] = vh;
            *(s16x8*)&Cl[o] = vl;
        }
    }
}

// ---------------------------------------------------------------------------
// out = V0 @ W_out + b_out, N=10. One wave per batch row; V0 from planes.
// ---------------------------------------------------------------------------
__global__ __launch_bounds__(256) void out_gemm(
    const u16* __restrict__ V0h, const u16* __restrict__ V0l,
    const float* __restrict__ Wout,
    const float* __restrict__ bout, float* __restrict__ out)
{
    __shared__ float Ws[NU*NDOUT];
    const int t = threadIdx.x;
    for (int i = t; i < NU*NDOUT; i += 256) Ws[i] = Wout[i];
    __syncthreads();
    const int lane = t & 63;
    const int wv = t >> 6;
    const int row = blockIdx.x*4 + wv;
    float acc[NDOUT];
#pragma unroll
    for (int j = 0; j < NDOUT; ++j) acc[j] = 0.0f;
#pragma unroll
    for (int s = 0; s < 4; ++s) {
        const int k = lane + 64*s;
        const size_t o = (size_t)row*NU + k;
        const float v = bf2f(V0h[o]) + bf2f(V0l[o]);
#pragma unroll
        for (int j = 0; j < NDOUT; ++j) acc[j] = fmaf(v, Ws[k*NDOUT + j], acc[j]);
    }
#pragma unroll
    for (int off = 32; off > 0; off >>= 1) {
#pragma unroll
        for (int j = 0; j < NDOUT; ++j) acc[j] += __shfl_down(acc[j], off);
    }
    if (lane == 0) {
#pragma unroll
        for (int j = 0; j < NDOUT; ++j) out[(size_t)row*NDOUT + j] = acc[j] + bout[j];
    }
}

extern "C" void kernel_launch(void* const* d_in, const int* in_sizes, int n_in,
                              void* d_out, int out_size, void* d_ws, size_t ws_size,
                              hipStream_t stream)
{
    const float* x    = (const float*)d_in[0];
    const float* Win  = (const float*)d_in[1];
    const float* bin  = (const float*)d_in[2];
    const float* B0   = (const float*)d_in[3];
    const float* q    = (const float*)d_in[4];
    const float* Wout = (const float*)d_in[5];
    const float* bout = (const float*)d_in[6];
    float* out = (float*)d_out;

    // workspace carve (~104 MB)
    u16* wnnh = (u16*)d_ws;
    u16* wnnl = wnnh + (size_t)NLAYERS*NUSQ;
    u16* wnth = wnnl + (size_t)NLAYERS*NUSQ;
    u16* wntl = wnth + (size_t)NLAYERS*NUSQ;
    float* bq = (float*)(wntl + (size_t)NLAYERS*NUSQ);
    u16* pl   = (u16*)(bq + NLAYERS*NU);
    const size_t PSZ = (size_t)NBATCH*NU;
    u16* sAh = pl;           u16* sAl = sAh + PSZ;   // slot A (V0)
    u16* sBh = sAl + PSZ;    u16* sBl = sBh + PSZ;   // slot B (V1)
    u16* sCh = sBl + PSZ;    u16* sCl = sCh + PSZ;   // slot C (free)

    // fused: 6 invert blocks + 512 in_gemm blocks, concurrent
    fused_inv_ingemm<<<NLAYERS + 512, 512, 0, stream>>>(
        B0, q, wnnh, wnnl, wnth, wntl, bq,
        x, Win, bin, sAh, sAl, sBh, sBl);

    const dim3 ggrid(NBATCH/128, NU/128);   // 256 x 2

    u16 *v0h = sAh, *v0l = sAl, *v1h = sBh, *v1l = sBl, *frh = sCh, *frl = sCl;
    for (int l = 0; l < NLAYERS; ++l) {
        const size_t wo = (size_t)l*NUSQ;
        // newV0 = -V1 @ M
        gemm_mfma<<<ggrid, 256, 0, stream>>>(v1h, v1l, wnnh + wo, wnnl + wo,
                                             frh, frl, nullptr, -1.0f);
        // newV1 = V0 @ M^T + (Mq)^T
        gemm_mfma<<<ggrid, 256, 0, stream>>>(v0h, v0l, wnth + wo, wntl + wo,
                                             v1h, v1l, bq + (size_t)l*NU, 1.0f);
        u16* t0 = v0h; u16* t1 = v0l;
        v0h = frh; v0l = frl; frh = t0; frl = t1;
    }
    out_gemm<<<NBATCH/4, 256, 0, stream>>>(v0h, v0l, Wout, bout, out);
}

// Round 11
// 837.835 us; speedup vs baseline: 1.1058x; 1.0454x over previous
//
#include <hip/hip_runtime.h>
#include <math.h>

#define NU      256
#define NLAYERS 6
#define NBATCH  32768
#define NDIN    784
#define NDOUT   10
#define NUSQ    65536

typedef unsigned short u16;
typedef __attribute__((ext_vector_type(8))) short s16x8;
typedef __attribute__((ext_vector_type(4))) float f32x4;
typedef __attribute__((ext_vector_type(2))) float f32x2;

// bf16 helpers (RNE)
__device__ __forceinline__ u16 f2bf(float x) {
    union { float f; unsigned u; } a; a.f = x;
    const unsigned r = a.u + 0x7fffu + ((a.u >> 16) & 1u);
    return (u16)(r >> 16);
}
__device__ __forceinline__ float bf2f(u16 h) {
    union { unsigned u; float f; } a; a.u = ((unsigned)h) << 16; return a.f;
}

// async global->LDS, 16 B per lane (m97 pattern; LDS dest = wave base + lane*16)
__device__ __forceinline__ void gl_lds16(const u16* g, u16* l) {
    __builtin_amdgcn_global_load_lds(
        (const __attribute__((address_space(1))) void*)g,
        (__attribute__((address_space(3))) void*)l, 16, 0, 0);
}

// uniform-lane float readlane (lane index must be wave-uniform)
__device__ __forceinline__ float rlf(float v, int lane) {
    return __int_as_float(__builtin_amdgcn_readlane(__float_as_int(v), lane));
}

// packed argmax key: |v| bits (top 24) | row (8 bits). unsigned-max == argmax.
__device__ __forceinline__ unsigned pkey(float v, int row) {
    return (__float_as_uint(fabsf(v)) & 0xFFFFFF00u) | (unsigned)row;
}

// wave64 unsigned-max reduce, pure VALU via DPP (no LDS pipe).
// row_shr 1/2/4/8 + row_bcast15 + row_bcast31. Result valid in lane 63.
__device__ __forceinline__ unsigned dpp_umax64_lane63(unsigned key) {
    unsigned t;
    t = (unsigned)__builtin_amdgcn_update_dpp(0, (int)key, 0x111, 0xf, 0xf, false); // row_shr:1
    key = key > t ? key : t;
    t = (unsigned)__builtin_amdgcn_update_dpp(0, (int)key, 0x112, 0xf, 0xf, false); // row_shr:2
    key = key > t ? key : t;
    t = (unsigned)__builtin_amdgcn_update_dpp(0, (int)key, 0x114, 0xf, 0xf, false); // row_shr:4
    key = key > t ? key : t;
    t = (unsigned)__builtin_amdgcn_update_dpp(0, (int)key, 0x118, 0xf, 0xf, false); // row_shr:8
    key = key > t ? key : t;
    t = (unsigned)__builtin_amdgcn_update_dpp(0, (int)key, 0x142, 0xf, 0xf, false); // row_bcast:15
    key = key > t ? key : t;
    t = (unsigned)__builtin_amdgcn_update_dpp(0, (int)key, 0x143, 0xf, 0xf, false); // row_bcast:31
    key = key > t ? key : t;
    return key;
}

// 32-way static-index dispatch over a wave-uniform column index.
#define COL_CASES(BODY) \
    case 0:  BODY(0);  break; case 1:  BODY(1);  break; \
    case 2:  BODY(2);  break; case 3:  BODY(3);  break; \
    case 4:  BODY(4);  break; case 5:  BODY(5);  break; \
    case 6:  BODY(6);  break; case 7:  BODY(7);  break; \
    case 8:  BODY(8);  break; case 9:  BODY(9);  break; \
    case 10: BODY(10); break; case 11: BODY(11); break; \
    case 12: BODY(12); break; case 13: BODY(13); break; \
    case 14: BODY(14); break; case 15: BODY(15); break; \
    case 16: BODY(16); break; case 17: BODY(17); break; \
    case 18: BODY(18); break; case 19: BODY(19); break; \
    case 20: BODY(20); break; case 21: BODY(21); break; \
    case 22: BODY(22); break; case 23: BODY(23); break; \
    case 24: BODY(24); break; case 25: BODY(25); break; \
    case 26: BODY(26); break; case 27: BODY(27); break; \
    case 28: BODY(28); break; case 29: BODY(29); break; \
    case 30: BODY(30); break; case 31: BODY(31); break;

// ---------------------------------------------------------------------------
// Fused first kernel: blocks 0..5 = GJ inversion (r5-proven: DPP argmax +
// readlane broadcast, no per-step DS traffic); blocks 6..517 = in_gemm
// (r0-proven fp32 body, threads>=256 exit).  BYTE-IDENTICAL to rounds 5-10.
// ---------------------------------------------------------------------------
__global__ __launch_bounds__(512, 2) void fused_inv_ingemm(
    const float* __restrict__ B0, const float* __restrict__ qg,
    u16* __restrict__ wnnh, u16* __restrict__ wnnl,
    u16* __restrict__ wnth, u16* __restrict__ wntl,
    float* __restrict__ bq,
    const float* __restrict__ X, const float* __restrict__ Win,
    const float* __restrict__ bin,
    u16* __restrict__ V0h, u16* __restrict__ V0l,
    u16* __restrict__ V1h, u16* __restrict__ V1l)
{
    // ---- invert LDS ----
    __shared__ __align__(16) float colv[2][256];
    __shared__ int   s_p[2];
    __shared__ float s_pv[2];
    __shared__ int   pivrow[256];
    __shared__ int   ilogrow[256];
    __shared__ float qs[256];
    __shared__ float part[8][256];
    // ---- in_gemm LDS ----
    __shared__ __align__(16) float As[16][128];
    __shared__ __align__(16) float Bs[16][128];

    const int tid = threadIdx.x;

    if (blockIdx.x < NLAYERS) {
        // =================== inversion path ===================
        const int layer = blockIdx.x;
        const int ct = tid & 63;     // lane: owns rows ct*4 .. ct*4+3
        const int wv = tid >> 6;     // wave: owns cols wv*32 .. wv*32+31

        float a[32][4];
        const float* Ablk = B0 + (size_t)layer * NU * NU;
#pragma unroll
        for (int j = 0; j < 4; ++j) {
            const float* rp = Ablk + (size_t)(ct*4 + j)*NU + wv*32;
#pragma unroll
            for (int i = 0; i < 32; i += 4) {
                const float4 v = *(const float4*)(rp + i);
                a[i+0][j] = v.x; a[i+1][j] = v.y; a[i+2][j] = v.z; a[i+3][j] = v.w;
            }
        }

        int used = 0;

        for (int k = 0; k < 256; ++k) {
            const int wvk = k >> 5, ikk = k & 31, buf = k & 1;

            if (wv == wvk) {
                float c0, c1, c2, c3;
#define EXT(I) { c0 = a[I][0]; c1 = a[I][1]; c2 = a[I][2]; c3 = a[I][3]; }
                switch (ikk) { COL_CASES(EXT) }
#undef EXT
                // packed-key argmax over unused rows, pure-VALU DPP reduce
                unsigned key = (used & 1) ? 0u : pkey(c0, ct*4 + 0);
                unsigned q1  = (used & 2) ? 0u : pkey(c1, ct*4 + 1); key = key > q1 ? key : q1;
                unsigned q2  = (used & 4) ? 0u : pkey(c2, ct*4 + 2); key = key > q2 ? key : q2;
                unsigned q3  = (used & 8) ? 0u : pkey(c3, ct*4 + 3); key = key > q3 ? key : q3;
                key = dpp_umax64_lane63(key);
                const int pn = __builtin_amdgcn_readlane((int)key, 63) & 255;
                float bv;
                switch (pn & 3) {
                    case 0: bv = rlf(c0, pn >> 2); break;
                    case 1: bv = rlf(c1, pn >> 2); break;
                    case 2: bv = rlf(c2, pn >> 2); break;
                    default: bv = rlf(c3, pn >> 2); break;
                }
                float4 cw; cw.x = c0; cw.y = c1; cw.z = c2; cw.w = c3;
                *(float4*)(&colv[buf][ct*4]) = cw;
                if (ct == 0) {
                    s_p[buf] = pn;
                    s_pv[buf] = 1.0f / bv;
                    pivrow[k] = pn;
                }
            }
            __syncthreads();

            const int   p      = __builtin_amdgcn_readfirstlane(s_p[buf]);
            const float pivinv = s_pv[buf];
            const int ctp = p >> 2, jp = p & 3;

            const float4 dv = *(const float4*)(&colv[buf][ct*4]);

            // pivot-row broadcast via v_readlane (VALU pipe; no ds_bpermute)
            float prw[32];
#define BRD(J) { _Pragma("unroll") for (int i = 0; i < 32; ++i) \
                    prw[i] = rlf(a[i][J], ctp) * pivinv; }
            switch (jp) {
                case 0: BRD(0) break; case 1: BRD(1) break;
                case 2: BRD(2) break; default: BRD(3) break;
            }
#undef BRD

            if (wv == wvk) {   // column-k special case ONLY in the owning wave
#define ZCOL(I) { prw[I] = pivinv; a[I][0] = 0.0f; a[I][1] = 0.0f; a[I][2] = 0.0f; a[I][3] = 0.0f; }
                switch (ikk) { COL_CASES(ZCOL) }
#undef ZCOL
            }

            const float d0 = -dv.x, d1 = -dv.y, d2 = -dv.z, d3 = -dv.w;
#pragma unroll
            for (int i = 0; i < 32; ++i) {
                const float pw = prw[i];
                a[i][0] = fmaf(d0, pw, a[i][0]);
                a[i][1] = fmaf(d1, pw, a[i][1]);
                a[i][2] = fmaf(d2, pw, a[i][2]);
                a[i][3] = fmaf(d3, pw, a[i][3]);
            }

            const bool mine = (ct == ctp);
#define OWR(J) { _Pragma("unroll") for (int i = 0; i < 32; ++i) a[i][J] = mine ? prw[i] : a[i][J]; }
            switch (jp) {
                case 0: OWR(0) break; case 1: OWR(1) break;
                case 2: OWR(2) break; default: OWR(3) break;
            }
#undef OWR
            if (mine) used |= (1 << jp);
        }
        __syncthreads();

        // stored a[i][j] = M[r][c], r = ilog[ct*4+j], c = pivrow[wv*32+i]
        if (tid < 256) { ilogrow[pivrow[tid]] = tid; qs[tid] = qg[(size_t)layer*NU + tid]; }
        __syncthreads();

        // ---- bq = M q ----
        {
            float s0=0.f, s1=0.f, s2=0.f, s3=0.f;
#pragma unroll
            for (int i = 0; i < 32; ++i) {
                const float qq = qs[pivrow[wv*32 + i]];
                s0 = fmaf(a[i][0], qq, s0);
                s1 = fmaf(a[i][1], qq, s1);
                s2 = fmaf(a[i][2], qq, s2);
                s3 = fmaf(a[i][3], qq, s3);
            }
            part[wv][ct*4+0] = s0; part[wv][ct*4+1] = s1;
            part[wv][ct*4+2] = s2; part[wv][ct*4+3] = s3;
        }
        __syncthreads();
        if (tid < 256) {
            float s = 0.f;
#pragma unroll
            for (int w2 = 0; w2 < 8; ++w2) s += part[w2][tid];
            bq[(size_t)layer*NU + ilogrow[tid]] = s;
        }

        // ---- split-bf16 W planes ----
        u16* nh = wnnh + (size_t)layer*NUSQ; u16* nl = wnnl + (size_t)layer*NUSQ;
        u16* th = wnth + (size_t)layer*NUSQ; u16* tl = wntl + (size_t)layer*NUSQ;
#pragma unroll
        for (int j = 0; j < 4; ++j) {
            const int r = ilogrow[ct*4 + j];
#pragma unroll
            for (int i = 0; i < 32; ++i) {
                const int c = pivrow[wv*32 + i];
                const float v = a[i][j];
                const u16 h  = f2bf(v);
                const u16 lo = f2bf(v - bf2f(h));
                th[(size_t)r*NU + c] = h;  tl[(size_t)r*NU + c] = lo;  // wnt[n][k]=M[n][k]
                nh[(size_t)c*NU + r] = h;  nl[(size_t)c*NU + r] = lo;  // wnn[n][k]=M[k][n]
            }
        }
        return;
    }

    // =================== in_gemm path (256 active threads) ===================
    if (tid >= 256) return;   // exited waves free their slots; HW barrier counts rest

    const int bid = blockIdx.x - NLAYERS;
    const int m0 = (bid & 255) * 128;
    const int n0 = (bid >> 8) * 128;
    const int t  = tid;
    const int tx = t & 15, ty = t >> 4;
    const int K = NDIN;

    float acc[8][8];
#pragma unroll
    for (int i = 0; i < 8; ++i)
#pragma unroll
        for (int j = 0; j < 8; ++j) acc[i][j] = 0.0f;

    const int am = t >> 1;
    const int ak = (t & 1) * 8;
    const int bk = t >> 4;
    const int bn = (t & 15) * 8;

    for (int k0 = 0; k0 < K; k0 += 16) {
        const float* Ap = X + (size_t)(m0 + am)*K + (k0 + ak);
        const float4 a0 = *(const float4*)(Ap);
        const float4 a1 = *(const float4*)(Ap + 4);
        As[ak+0][am] = a0.x; As[ak+1][am] = a0.y; As[ak+2][am] = a0.z; As[ak+3][am] = a0.w;
        As[ak+4][am] = a1.x; As[ak+5][am] = a1.y; As[ak+6][am] = a1.z; As[ak+7][am] = a1.w;
        const float* Bp = Win + (size_t)(k0 + bk)*NU + (n0 + bn);
        const float4 b0 = *(const float4*)(Bp);
        const float4 b1 = *(const float4*)(Bp + 4);
        *(float4*)(&Bs[bk][bn])   = b0;
        *(float4*)(&Bs[bk][bn+4]) = b1;
        __syncthreads();
#pragma unroll
        for (int kk = 0; kk < 16; ++kk) {
            float af[8], bf[8];
            *(float4*)(af)   = *(const float4*)(&As[kk][ty*8]);
            *(float4*)(af+4) = *(const float4*)(&As[kk][ty*8+4]);
            *(float4*)(bf)   = *(const float4*)(&Bs[kk][tx*8]);
            *(float4*)(bf+4) = *(const float4*)(&Bs[kk][tx*8+4]);
#pragma unroll
            for (int i = 0; i < 8; ++i)
#pragma unroll
                for (int j = 0; j < 8; ++j)
                    acc[i][j] = fmaf(af[i], bf[j], acc[i][j]);
        }
        __syncthreads();
    }

#pragma unroll
    for (int i = 0; i < 8; ++i) {
        const size_t row = m0 + ty*8 + i;
        s16x8 vh, vl, th2, tl2;
#pragma unroll
        for (int j = 0; j < 8; ++j) {
            const float v = acc[i][j] + bin[n0 + tx*8 + j];
            const u16 h  = f2bf(v);
            vh[j] = (short)h; vl[j] = (short)f2bf(v - bf2f(h));
            const float tv = tanhf(v);
            const u16 h2 = f2bf(tv);
            th2[j] = (short)h2; tl2[j] = (short)f2bf(tv - bf2f(h2));
        }
        const size_t o = row*NU + n0 + tx*8;
        *(s16x8*)&V0h[o] = vh; *(s16x8*)&V0l[o] = vl;
        *(s16x8*)&V1h[o] = th2; *(s16x8*)&V1l[o] = tl2;
    }
}

// Shared GEMM body (textual macro so the LDS arrays stay kernel-local and
// gl_lds16 sees direct __shared__ references -- no device-function LDS
// pointer passing). Body is byte-for-byte the r10-proven kernel interior.
#define GEMM_BODY(Ah, Al, Bh, Bl, Ch, Cl, bias, alpha, MB, NB)                 \
    const int t    = threadIdx.x;                                              \
    const int lane = t & 63;                                                   \
    const int w    = t >> 6;                                                   \
    const int wr = w >> 1, wc = w & 1;                                         \
    const int qd = lane >> 4, l15 = lane & 15;                                 \
    const int m0 = (MB) * 128, n0 = (NB) * 128;                                \
    const int srow = t >> 2;                                                   \
    const int skc  = (t & 3) * 8;                                              \
    f32x4 acc[4][4];                                                           \
    const f32x4 z = {0.f, 0.f, 0.f, 0.f};                                      \
    _Pragma("unroll") for (int i = 0; i < 4; ++i)                              \
        _Pragma("unroll") for (int j = 0; j < 4; ++j) acc[i][j] = z;           \
    for (int k0 = 0; k0 < NU; k0 += 32) {                                      \
        _Pragma("unroll") for (int half = 0; half < 2; ++half) {               \
            const int rr = srow + half*64;                                     \
            const size_t ga = (size_t)(m0 + rr)*NU + k0 + skc;                 \
            const size_t gb = (size_t)(n0 + rr)*NU + k0 + skc;                 \
            const int lo = rr*32 + skc;                                        \
            gl_lds16((Ah) + ga, &lAh[lo]);                                     \
            gl_lds16((Al) + ga, &lAl[lo]);                                     \
            gl_lds16((Bh) + gb, &lBh[lo]);                                     \
            gl_lds16((Bl) + gb, &lBl[lo]);                                     \
        }                                                                      \
        __syncthreads();                                                       \
        s16x8 ah[4], al[4], bh[4], bl[4];                                      \
        _Pragma("unroll") for (int mt = 0; mt < 4; ++mt) {                     \
            const int off = (wr*64 + mt*16 + l15)*32 + qd*8;                   \
            ah[mt] = *(const s16x8*)&lAh[off];                                 \
            al[mt] = *(const s16x8*)&lAl[off];                                 \
        }                                                                      \
        _Pragma("unroll") for (int nt = 0; nt < 4; ++nt) {                     \
            const int off = (wc*64 + nt*16 + l15)*32 + qd*8;                   \
            bh[nt] = *(const s16x8*)&lBh[off];                                 \
            bl[nt] = *(const s16x8*)&lBl[off];                                 \
        }                                                                      \
        _Pragma("unroll") for (int mt = 0; mt < 4; ++mt)                       \
            _Pragma("unroll") for (int nt = 0; nt < 4; ++nt) {                 \
                acc[mt][nt] = __builtin_amdgcn_mfma_f32_16x16x32_bf16(ah[mt], bh[nt], acc[mt][nt], 0, 0, 0); \
                acc[mt][nt] = __builtin_amdgcn_mfma_f32_16x16x32_bf16(ah[mt], bl[nt], acc[mt][nt], 0, 0, 0); \
                acc[mt][nt] = __builtin_amdgcn_mfma_f32_16x16x32_bf16(al[mt], bh[nt], acc[mt][nt], 0, 0, 0); \
            }                                                                  \
        __syncthreads();                                                       \
    }                                                                          \
    float bb[4];                                                               \
    _Pragma("unroll") for (int nt = 0; nt < 4; ++nt) {                         \
        const int col = n0 + wc*64 + nt*16 + l15;                              \
        bb[nt] = (bias) ? (bias)[col] : 0.0f;                                  \
    }                                                                          \
    float* zone = &fbuf[w*2112];                                               \
    const int s8 = lane >> 3;                                                  \
    const int c8 = (lane & 7) * 8;                                             \
    _Pragma("unroll") for (int p = 0; p < 2; ++p) {                            \
        _Pragma("unroll") for (int mt2 = 0; mt2 < 2; ++mt2) {                  \
            const int mt = 2*p + mt2;                                          \
            _Pragma("unroll") for (int nt = 0; nt < 4; ++nt)                   \
                _Pragma("unroll") for (int r = 0; r < 4; ++r)                  \
                    zone[(mt2*16 + qd*4 + r)*66 + nt*16 + l15] =               \
                        (alpha)*acc[mt][nt][r] + bb[nt];                       \
        }                                                                      \
        _Pragma("unroll") for (int u = 0; u < 4; ++u) {                        \
            const int rl = u*8 + s8;                                           \
            const float* src = &zone[rl*66 + c8];                              \
            float v8[8];                                                       \
            *(f32x2*)(v8)   = *(const f32x2*)(src);                            \
            *(f32x2*)(v8+2) = *(const f32x2*)(src+2);                          \
            *(f32x2*)(v8+4) = *(const f32x2*)(src+4);                          \
            *(f32x2*)(v8+6) = *(const f32x2*)(src+6);                          \
            s16x8 vh, vl;                                                      \
            _Pragma("unroll") for (int j = 0; j < 8; ++j) {                    \
                const u16 h = f2bf(v8[j]);                                     \
                vh[j] = (short)h;                                              \
                vl[j] = (short)f2bf(v8[j] - bf2f(h));                          \
            }                                                                  \
            const size_t o = (size_t)(m0 + wr*64 + p*32 + rl)*NU + (n0 + wc*64 + c8); \
            *(s16x8*)&(Ch)[o] = vh;                                            \
            *(s16x8*)&(Cl)[o] = vl;                                            \
        }                                                                      \
    }

// ---------------------------------------------------------------------------
// Single GEMM (r10-proven): 128x128 tile, grid (256,2).
// ---------------------------------------------------------------------------
__global__ __launch_bounds__(256, 2) void gemm_mfma(
    const u16* __restrict__ Ah, const u16* __restrict__ Al,
    const u16* __restrict__ Bh, const u16* __restrict__ Bl,
    u16* __restrict__ Ch, u16* __restrict__ Cl,
    const float* __restrict__ bias, const float alpha)
{
    __shared__ __align__(16) u16 lAh[128*32], lAl[128*32], lBh[128*32], lBl[128*32];
    __shared__ __align__(16) float fbuf[4*2112];
    GEMM_BODY(Ah, Al, Bh, Bl, Ch, Cl, bias, alpha, blockIdx.x, blockIdx.y)
}

// ---------------------------------------------------------------------------
// Pair GEMM: grid (256,2,2). z=0: C1 = -A1@B1 ; z=1: C2 = A2@B2 + bias2.
// Same body; wave-uniform pointer select at top. The two halves are
// data-independent (4 distinct plane slots).
// ---------------------------------------------------------------------------
__global__ __launch_bounds__(256, 2) void gemm_pair(
    const u16* __restrict__ A1h, const u16* __restrict__ A1l,
    const u16* __restrict__ B1h, const u16* __restrict__ B1l,
    u16* __restrict__ C1h, u16* __restrict__ C1l,
    const u16* __restrict__ A2h, const u16* __restrict__ A2l,
    const u16* __restrict__ B2h, const u16* __restrict__ B2l,
    u16* __restrict__ C2h, u16* __restrict__ C2l,
    const float* __restrict__ bias2)
{
    __shared__ __align__(16) u16 lAh[128*32], lAl[128*32], lBh[128*32], lBl[128*32];
    __shared__ __align__(16) float fbuf[4*2112];
    const int pr = blockIdx.z;
    const u16* Ah = pr ? A2h : A1h;  const u16* Al = pr ? A2l : A1l;
    const u16* Bh = pr ? B2h : B1h;  const u16* Bl = pr ? B2l : B1l;
    u16* Ch = pr ? C2h : C1h;        u16* Cl = pr ? C2l : C1l;
    const float* bias = pr ? bias2 : nullptr;
    const float alpha = pr ? 1.0f : -1.0f;
    GEMM_BODY(Ah, Al, Bh, Bl, Ch, Cl, bias, alpha, blockIdx.x, blockIdx.y)
}

// ---------------------------------------------------------------------------
// out = V0 @ W_out + b_out, N=10. One wave per batch row; V0 from planes.
// ---------------------------------------------------------------------------
__global__ __launch_bounds__(256) void out_gemm(
    const u16* __restrict__ V0h, const u16* __restrict__ V0l,
    const float* __restrict__ Wout,
    const float* __restrict__ bout, float* __restrict__ out)
{
    __shared__ float Ws[NU*NDOUT];
    const int t = threadIdx.x;
    for (int i = t; i < NU*NDOUT; i += 256) Ws[i] = Wout[i];
    __syncthreads();
    const int lane = t & 63;
    const int wv = t >> 6;
    const int row = blockIdx.x*4 + wv;
    float acc[NDOUT];
#pragma unroll
    for (int j = 0; j < NDOUT; ++j) acc[j] = 0.0f;
#pragma unroll
    for (int s = 0; s < 4; ++s) {
        const int k = lane + 64*s;
        const size_t o = (size_t)row*NU + k;
        const float v = bf2f(V0h[o]) + bf2f(V0l[o]);
#pragma unroll
        for (int j = 0; j < NDOUT; ++j) acc[j] = fmaf(v, Ws[k*NDOUT + j], acc[j]);
    }
#pragma unroll
    for (int off = 32; off > 0; off >>= 1) {
#pragma unroll
        for (int j = 0; j < NDOUT; ++j) acc[j] += __shfl_down(acc[j], off);
    }
    if (lane == 0) {
#pragma unroll
        for (int j = 0; j < NDOUT; ++j) out[(size_t)row*NDOUT + j] = acc[j] + bout[j];
    }
}

extern "C" void kernel_launch(void* const* d_in, const int* in_sizes, int n_in,
                              void* d_out, int out_size, void* d_ws, size_t ws_size,
                              hipStream_t stream)
{
    const float* x    = (const float*)d_in[0];
    const float* Win  = (const float*)d_in[1];
    const float* bin  = (const float*)d_in[2];
    const float* B0   = (const float*)d_in[3];
    const float* q    = (const float*)d_in[4];
    const float* Wout = (const float*)d_in[5];
    const float* bout = (const float*)d_in[6];
    float* out = (float*)d_out;

    // workspace carve
    u16* wnnh = (u16*)d_ws;
    u16* wnnl = wnnh + (size_t)NLAYERS*NUSQ;
    u16* wnth = wnnl + (size_t)NLAYERS*NUSQ;
    u16* wntl = wnth + (size_t)NLAYERS*NUSQ;
    float* bq = (float*)(wntl + (size_t)NLAYERS*NUSQ);
    u16* pl   = (u16*)(bq + NLAYERS*NU);
    const size_t PSZ = (size_t)NBATCH*NU;

    // plane slots (h,l per slot). 3 slots (~104 MB) always assumed; 4th slot
    // (~137 MB total) enables pair-fused dispatches.
    u16* sh[4]; u16* sl[4];
    for (int s = 0; s < 4; ++s) { sh[s] = pl + (size_t)(2*s)*PSZ; sl[s] = pl + (size_t)(2*s+1)*PSZ; }
    const size_t base_bytes = (size_t)((char*)pl - (char*)d_ws);
    const bool has4 = ws_size >= base_bytes + 8*PSZ*sizeof(u16);

    // fused: 6 invert blocks + 512 in_gemm blocks, concurrent
    fused_inv_ingemm<<<NLAYERS + 512, 512, 0, stream>>>(
        B0, q, wnnh, wnnl, wnth, wntl, bq,
        x, Win, bin, sh[0], sl[0], sh[1], sl[1]);

    const dim3 ggrid(NBATCH/128, NU/128);      // 256 x 2
    const dim3 pgrid(NBATCH/128, NU/128, 2);   // 256 x 2 x 2

    if (has4) {
        int iv0 = 0, iv1 = 1, f0 = 2, f1 = 3;
        for (int l = 0; l < NLAYERS - 1; ++l) {
            const size_t wo = (size_t)l*NUSQ;
            gemm_pair<<<pgrid, 256, 0, stream>>>(
                sh[iv1], sl[iv1], wnnh + wo, wnnl + wo, sh[f0], sl[f0],   // newV0 = -V1 @ M
                sh[iv0], sl[iv0], wnth + wo, wntl + wo, sh[f1], sl[f1],   // newV1 = V0 @ M^T + bq
                bq + (size_t)l*NU);
            const int t0 = iv0, t1 = iv1;
            iv0 = f0; iv1 = f1; f0 = t0; f1 = t1;
        }
        // layer 5: only newV0 is needed by the output
        const size_t wo = (size_t)(NLAYERS - 1)*NUSQ;
        gemm_mfma<<<ggrid, 256, 0, stream>>>(sh[iv1], sl[iv1], wnnh + wo, wnnl + wo,
                                             sh[f0], sl[f0], nullptr, -1.0f);
        out_gemm<<<NBATCH/4, 256, 0, stream>>>(sh[f0], sl[f0], Wout, bout, out);
    } else {
        u16 *v0h = sh[0], *v0l = sl[0], *v1h = sh[1], *v1l = sl[1], *frh = sh[2], *frl = sl[2];
        for (int l = 0; l < NLAYERS; ++l) {
            const size_t wo = (size_t)l*NUSQ;
            gemm_mfma<<<ggrid, 256, 0, stream>>>(v1h, v1l, wnnh + wo, wnnl + wo,
                                                 frh, frl, nullptr, -1.0f);
            if (l < NLAYERS - 1)   // layer 5's newV1 is dead
                gemm_mfma<<<ggrid, 256, 0, stream>>>(v0h, v0l, wnth + wo, wntl + wo,
                                                     v1h, v1l, bq + (size_t)l*NU, 1.0f);
            u16* t0 = v0h; u16* t1 = v0l;
            v0h = frh; v0l = frl; frh = t0; frl = t1;
        }
        out_gemm<<<NBATCH/4, 256, 0, stream>>>(v0h, v0l, Wout, bout, out);
    }
}

// Round 12
// 826.663 us; speedup vs baseline: 1.1208x; 1.0135x over previous
//
#include <hip/hip_runtime.h>
#include <math.h>

#define NU      256
#define NLAYERS 6
#define NBATCH  32768
#define NDIN    784
#define NDOUT   10
#define NUSQ    65536

typedef unsigned short u16;
typedef __attribute__((ext_vector_type(8))) short s16x8;
typedef __attribute__((ext_vector_type(4))) float f32x4;
typedef __attribute__((ext_vector_type(2))) float f32x2;

// bf16 helpers (RNE)
__device__ __forceinline__ u16 f2bf(float x) {
    union { float f; unsigned u; } a; a.f = x;
    const unsigned r = a.u + 0x7fffu + ((a.u >> 16) & 1u);
    return (u16)(r >> 16);
}
__device__ __forceinline__ float bf2f(u16 h) {
    union { unsigned u; float f; } a; a.u = ((unsigned)h) << 16; return a.f;
}

// async global->LDS, 16 B per lane (m97 pattern; LDS dest = wave base + lane*16)
__device__ __forceinline__ void gl_lds16(const u16* g, u16* l) {
    __builtin_amdgcn_global_load_lds(
        (const __attribute__((address_space(1))) void*)g,
        (__attribute__((address_space(3))) void*)l, 16, 0, 0);
}

// uniform-lane float readlane (lane index must be wave-uniform)
__device__ __forceinline__ float rlf(float v, int lane) {
    return __int_as_float(__builtin_amdgcn_readlane(__float_as_int(v), lane));
}

// packed argmax key: |v| bits (top 24) | row (8 bits). unsigned-max == argmax.
__device__ __forceinline__ unsigned pkey(float v, int row) {
    return (__float_as_uint(fabsf(v)) & 0xFFFFFF00u) | (unsigned)row;
}

// wave64 unsigned-max reduce, pure VALU via DPP (no LDS pipe).
// row_shr 1/2/4/8 + row_bcast15 + row_bcast31. Result valid in lane 63.
__device__ __forceinline__ unsigned dpp_umax64_lane63(unsigned key) {
    unsigned t;
    t = (unsigned)__builtin_amdgcn_update_dpp(0, (int)key, 0x111, 0xf, 0xf, false); // row_shr:1
    key = key > t ? key : t;
    t = (unsigned)__builtin_amdgcn_update_dpp(0, (int)key, 0x112, 0xf, 0xf, false); // row_shr:2
    key = key > t ? key : t;
    t = (unsigned)__builtin_amdgcn_update_dpp(0, (int)key, 0x114, 0xf, 0xf, false); // row_shr:4
    key = key > t ? key : t;
    t = (unsigned)__builtin_amdgcn_update_dpp(0, (int)key, 0x118, 0xf, 0xf, false); // row_shr:8
    key = key > t ? key : t;
    t = (unsigned)__builtin_amdgcn_update_dpp(0, (int)key, 0x142, 0xf, 0xf, false); // row_bcast:15
    key = key > t ? key : t;
    t = (unsigned)__builtin_amdgcn_update_dpp(0, (int)key, 0x143, 0xf, 0xf, false); // row_bcast:31
    key = key > t ? key : t;
    return key;
}

// 32-way static-index dispatch over a wave-uniform column index.
#define COL_CASES(BODY) \
    case 0:  BODY(0);  break; case 1:  BODY(1);  break; \
    case 2:  BODY(2);  break; case 3:  BODY(3);  break; \
    case 4:  BODY(4);  break; case 5:  BODY(5);  break; \
    case 6:  BODY(6);  break; case 7:  BODY(7);  break; \
    case 8:  BODY(8);  break; case 9:  BODY(9);  break; \
    case 10: BODY(10); break; case 11: BODY(11); break; \
    case 12: BODY(12); break; case 13: BODY(13); break; \
    case 14: BODY(14); break; case 15: BODY(15); break; \
    case 16: BODY(16); break; case 17: BODY(17); break; \
    case 18: BODY(18); break; case 19: BODY(19); break; \
    case 20: BODY(20); break; case 21: BODY(21); break; \
    case 22: BODY(22); break; case 23: BODY(23); break; \
    case 24: BODY(24); break; case 25: BODY(25); break; \
    case 26: BODY(26); break; case 27: BODY(27); break; \
    case 28: BODY(28); break; case 29: BODY(29); break; \
    case 30: BODY(30); break; case 31: BODY(31); break;

// ---------------------------------------------------------------------------
// Fused first kernel: blocks 0..5 = GJ inversion; blocks 6..517 = in_gemm
// (r0-proven fp32 body, threads>=256 exit).
// Inversion = r5-proven step (DPP argmax + readlane broadcast) with ONE
// structural change: single barrier per step. Phase-1 of step k+1 (extract
// col k+1, argmax, publish) runs in the OWNER wave's tail of step k, into
// the nbuf side of the already-double-buffered colv/s_p/s_pv. The owner's
// registers hold col k+1 updated through step k at that point, so the
// published values are bit-identical to r5's phase-1 one barrier later.
// `used` is updated by every wave in phase-2 before the tail. Saves one
// 8-wave barrier (drain+wake) per step, 256 steps.
// ---------------------------------------------------------------------------
__global__ __launch_bounds__(512, 2) void fused_inv_ingemm(
    const float* __restrict__ B0, const float* __restrict__ qg,
    u16* __restrict__ wnnh, u16* __restrict__ wnnl,
    u16* __restrict__ wnth, u16* __restrict__ wntl,
    float* __restrict__ bq,
    const float* __restrict__ X, const float* __restrict__ Win,
    const float* __restrict__ bin,
    u16* __restrict__ V0h, u16* __restrict__ V0l,
    u16* __restrict__ V1h, u16* __restrict__ V1l)
{
    // ---- invert LDS ----
    __shared__ __align__(16) float colv[2][256];
    __shared__ int   s_p[2];
    __shared__ float s_pv[2];
    __shared__ int   pivrow[256];
    __shared__ int   ilogrow[256];
    __shared__ float qs[256];
    __shared__ float part[8][256];
    // ---- in_gemm LDS ----
    __shared__ __align__(16) float As[16][128];
    __shared__ __align__(16) float Bs[16][128];

    const int tid = threadIdx.x;

    if (blockIdx.x < NLAYERS) {
        // =================== inversion path ===================
        const int layer = blockIdx.x;
        const int ct = tid & 63;     // lane: owns rows ct*4 .. ct*4+3
        const int wv = tid >> 6;     // wave: owns cols wv*32 .. wv*32+31

        float a[32][4];
        const float* Ablk = B0 + (size_t)layer * NU * NU;
#pragma unroll
        for (int j = 0; j < 4; ++j) {
            const float* rp = Ablk + (size_t)(ct*4 + j)*NU + wv*32;
#pragma unroll
            for (int i = 0; i < 32; i += 4) {
                const float4 v = *(const float4*)(rp + i);
                a[i+0][j] = v.x; a[i+1][j] = v.y; a[i+2][j] = v.z; a[i+3][j] = v.w;
            }
        }

        int used = 0;

#define EXT(I) { c0 = a[I][0]; c1 = a[I][1]; c2 = a[I][2]; c3 = a[I][3]; }
        // phase-1: extract col KIDX (within own slab), masked packed-key
        // argmax via DPP, recover pivot value via readlane, publish.
#define PHASE1_BODY(KIDX, PBUF) { \
            const int inx_ = (KIDX) & 31; \
            float c0, c1, c2, c3; \
            switch (inx_) { COL_CASES(EXT) } \
            unsigned key = (used & 1) ? 0u : pkey(c0, ct*4 + 0); \
            unsigned q1  = (used & 2) ? 0u : pkey(c1, ct*4 + 1); key = key > q1 ? key : q1; \
            unsigned q2  = (used & 4) ? 0u : pkey(c2, ct*4 + 2); key = key > q2 ? key : q2; \
            unsigned q3  = (used & 8) ? 0u : pkey(c3, ct*4 + 3); key = key > q3 ? key : q3; \
            key = dpp_umax64_lane63(key); \
            const int pn_ = __builtin_amdgcn_readlane((int)key, 63) & 255; \
            float bv_; \
            switch (pn_ & 3) { \
                case 0: bv_ = rlf(c0, pn_ >> 2); break; \
                case 1: bv_ = rlf(c1, pn_ >> 2); break; \
                case 2: bv_ = rlf(c2, pn_ >> 2); break; \
                default: bv_ = rlf(c3, pn_ >> 2); break; \
            } \
            float4 cw_; cw_.x = c0; cw_.y = c1; cw_.z = c2; cw_.w = c3; \
            *(float4*)(&colv[PBUF][ct*4]) = cw_; \
            if (ct == 0) { \
                s_p[PBUF] = pn_; \
                s_pv[PBUF] = 1.0f / bv_; \
                pivrow[KIDX] = pn_; \
            } \
        }

        // prologue: phase-1 for column 0 (wave 0, buffer 0)
        if (wv == 0) PHASE1_BODY(0, 0)
        __syncthreads();

        for (int k = 0; k < 256; ++k) {
            const int wvk = k >> 5, ikk = k & 31, buf = k & 1;

            const int   p      = __builtin_amdgcn_readfirstlane(s_p[buf]);
            const float pivinv = s_pv[buf];
            const int ctp = p >> 2, jp = p & 3;

            const float4 dv = *(const float4*)(&colv[buf][ct*4]);

            // pivot-row broadcast via v_readlane (VALU pipe; no ds_bpermute)
            float prw[32];
#define BRD(J) { _Pragma("unroll") for (int i = 0; i < 32; ++i) \
                    prw[i] = rlf(a[i][J], ctp) * pivinv; }
            switch (jp) {
                case 0: BRD(0) break; case 1: BRD(1) break;
                case 2: BRD(2) break; default: BRD(3) break;
            }
#undef BRD

            if (wv == wvk) {   // column-k special case ONLY in the owning wave
#define ZCOL(I) { prw[I] = pivinv; a[I][0] = 0.0f; a[I][1] = 0.0f; a[I][2] = 0.0f; a[I][3] = 0.0f; }
                switch (ikk) { COL_CASES(ZCOL) }
#undef ZCOL
            }

            const float d0 = -dv.x, d1 = -dv.y, d2 = -dv.z, d3 = -dv.w;
#pragma unroll
            for (int i = 0; i < 32; ++i) {
                const float pw = prw[i];
                a[i][0] = fmaf(d0, pw, a[i][0]);
                a[i][1] = fmaf(d1, pw, a[i][1]);
                a[i][2] = fmaf(d2, pw, a[i][2]);
                a[i][3] = fmaf(d3, pw, a[i][3]);
            }

            const bool mine = (ct == ctp);
#define OWR(J) { _Pragma("unroll") for (int i = 0; i < 32; ++i) a[i][J] = mine ? prw[i] : a[i][J]; }
            switch (jp) {
                case 0: OWR(0) break; case 1: OWR(1) break;
                case 2: OWR(2) break; default: OWR(3) break;
            }
#undef OWR
            if (mine) used |= (1 << jp);

            // ---- search-ahead tail: phase-1 of step k+1 in its owner wave,
            //      published into the other buffer; no one reads it until
            //      after the single end-of-step barrier.
            if (k < 255) {
                const int kn = k + 1;
                if (wv == (kn >> 5)) PHASE1_BODY(kn, (buf ^ 1))
            }
            __syncthreads();
        }
#undef PHASE1_BODY
#undef EXT
        __syncthreads();

        // stored a[i][j] = M[r][c], r = ilog[ct*4+j], c = pivrow[wv*32+i]
        if (tid < 256) { ilogrow[pivrow[tid]] = tid; qs[tid] = qg[(size_t)layer*NU + tid]; }
        __syncthreads();

        // ---- bq = M q ----
        {
            float s0=0.f, s1=0.f, s2=0.f, s3=0.f;
#pragma unroll
            for (int i = 0; i < 32; ++i) {
                const float qq = qs[pivrow[wv*32 + i]];
                s0 = fmaf(a[i][0], qq, s0);
                s1 = fmaf(a[i][1], qq, s1);
                s2 = fmaf(a[i][2], qq, s2);
                s3 = fmaf(a[i][3], qq, s3);
            }
            part[wv][ct*4+0] = s0; part[wv][ct*4+1] = s1;
            part[wv][ct*4+2] = s2; part[wv][ct*4+3] = s3;
        }
        __syncthreads();
        if (tid < 256) {
            float s = 0.f;
#pragma unroll
            for (int w2 = 0; w2 < 8; ++w2) s += part[w2][tid];
            bq[(size_t)layer*NU + ilogrow[tid]] = s;
        }

        // ---- split-bf16 W planes ----
        u16* nh = wnnh + (size_t)layer*NUSQ; u16* nl = wnnl + (size_t)layer*NUSQ;
        u16* th = wnth + (size_t)layer*NUSQ; u16* tl = wntl + (size_t)layer*NUSQ;
#pragma unroll
        for (int j = 0; j < 4; ++j) {
            const int r = ilogrow[ct*4 + j];
#pragma unroll
            for (int i = 0; i < 32; ++i) {
                const int c = pivrow[wv*32 + i];
                const float v = a[i][j];
                const u16 h  = f2bf(v);
                const u16 lo = f2bf(v - bf2f(h));
                th[(size_t)r*NU + c] = h;  tl[(size_t)r*NU + c] = lo;  // wnt[n][k]=M[n][k]
                nh[(size_t)c*NU + r] = h;  nl[(size_t)c*NU + r] = lo;  // wnn[n][k]=M[k][n]
            }
        }
        return;
    }

    // =================== in_gemm path (256 active threads) ===================
    if (tid >= 256) return;   // exited waves free their slots; HW barrier counts rest

    const int bid = blockIdx.x - NLAYERS;
    const int m0 = (bid & 255) * 128;
    const int n0 = (bid >> 8) * 128;
    const int t  = tid;
    const int tx = t & 15, ty = t >> 4;
    const int K = NDIN;

    float acc[8][8];
#pragma unroll
    for (int i = 0; i < 8; ++i)
#pragma unroll
        for (int j = 0; j < 8; ++j) acc[i][j] = 0.0f;

    const int am = t >> 1;
    const int ak = (t & 1) * 8;
    const int bk = t >> 4;
    const int bn = (t & 15) * 8;

    for (int k0 = 0; k0 < K; k0 += 16) {
        const float* Ap = X + (size_t)(m0 + am)*K + (k0 + ak);
        const float4 a0 = *(const float4*)(Ap);
        const float4 a1 = *(const float4*)(Ap + 4);
        As[ak+0][am] = a0.x; As[ak+1][am] = a0.y; As[ak+2][am] = a0.z; As[ak+3][am] = a0.w;
        As[ak+4][am] = a1.x; As[ak+5][am] = a1.y; As[ak+6][am] = a1.z; As[ak+7][am] = a1.w;
        const float* Bp = Win + (size_t)(k0 + bk)*NU + (n0 + bn);
        const float4 b0 = *(const float4*)(Bp);
        const float4 b1 = *(const float4*)(Bp + 4);
        *(float4*)(&Bs[bk][bn])   = b0;
        *(float4*)(&Bs[bk][bn+4]) = b1;
        __syncthreads();
#pragma unroll
        for (int kk = 0; kk < 16; ++kk) {
            float af[8], bf[8];
            *(float4*)(af)   = *(const float4*)(&As[kk][ty*8]);
            *(float4*)(af+4) = *(const float4*)(&As[kk][ty*8+4]);
            *(float4*)(bf)   = *(const float4*)(&Bs[kk][tx*8]);
            *(float4*)(bf+4) = *(const float4*)(&Bs[kk][tx*8+4]);
#pragma unroll
            for (int i = 0; i < 8; ++i)
#pragma unroll
                for (int j = 0; j < 8; ++j)
                    acc[i][j] = fmaf(af[i], bf[j], acc[i][j]);
        }
        __syncthreads();
    }

#pragma unroll
    for (int i = 0; i < 8; ++i) {
        const size_t row = m0 + ty*8 + i;
        s16x8 vh, vl, th2, tl2;
#pragma unroll
        for (int j = 0; j < 8; ++j) {
            const float v = acc[i][j] + bin[n0 + tx*8 + j];
            const u16 h  = f2bf(v);
            vh[j] = (short)h; vl[j] = (short)f2bf(v - bf2f(h));
            const float tv = tanhf(v);
            const u16 h2 = f2bf(tv);
            th2[j] = (short)h2; tl2[j] = (short)f2bf(tv - bf2f(h2));
        }
        const size_t o = row*NU + n0 + tx*8;
        *(s16x8*)&V0h[o] = vh; *(s16x8*)&V0l[o] = vl;
        *(s16x8*)&V1h[o] = th2; *(s16x8*)&V1l[o] = tl2;
    }
}

// Shared GEMM body (textual macro so the LDS arrays stay kernel-local and
// gl_lds16 sees direct __shared__ references -- no device-function LDS
// pointer passing). Body is byte-for-byte the r10-proven kernel interior.
#define GEMM_BODY(Ah, Al, Bh, Bl, Ch, Cl, bias, alpha, MB, NB)                 \
    const int t    = threadIdx.x;                                              \
    const int lane = t & 63;                                                   \
    const int w    = t >> 6;                                                   \
    const int wr = w >> 1, wc = w & 1;                                         \
    const int qd = lane >> 4, l15 = lane & 15;                                 \
    const int m0 = (MB) * 128, n0 = (NB) * 128;                                \
    const int srow = t >> 2;                                                   \
    const int skc  = (t & 3) * 8;                                              \
    f32x4 acc[4][4];                                                           \
    const f32x4 z = {0.f, 0.f, 0.f, 0.f};                                      \
    _Pragma("unroll") for (int i = 0; i < 4; ++i)                              \
        _Pragma("unroll") for (int j = 0; j < 4; ++j) acc[i][j] = z;           \
    for (int k0 = 0; k0 < NU; k0 += 32) {                                      \
        _Pragma("unroll") for (int half = 0; half < 2; ++half) {               \
            const int rr = srow + half*64;                                     \
            const size_t ga = (size_t)(m0 + rr)*NU + k0 + skc;                 \
            const size_t gb = (size_t)(n0 + rr)*NU + k0 + skc;                 \
            const int lo = rr*32 + skc;                                        \
            gl_lds16((Ah) + ga, &lAh[lo]);                                     \
            gl_lds16((Al) + ga, &lAl[lo]);                                     \
            gl_lds16((Bh) + gb, &lBh[lo]);                                     \
            gl_lds16((Bl) + gb, &lBl[lo]);                                     \
        }                                                                      \
        __syncthreads();                                                       \
        s16x8 ah[4], al[4], bh[4], bl[4];                                      \
        _Pragma("unroll") for (int mt = 0; mt < 4; ++mt) {                     \
            const int off = (wr*64 + mt*16 + l15)*32 + qd*8;                   \
            ah[mt] = *(const s16x8*)&lAh[off];                                 \
            al[mt] = *(const s16x8*)&lAl[off];                                 \
        }                                                                      \
        _Pragma("unroll") for (int nt = 0; nt < 4; ++nt) {                     \
            const int off = (wc*64 + nt*16 + l15)*32 + qd*8;                   \
            bh[nt] = *(const s16x8*)&lBh[off];                                 \
            bl[nt] = *(const s16x8*)&lBl[off];                                 \
        }                                                                      \
        _Pragma("unroll") for (int mt = 0; mt < 4; ++mt)                       \
            _Pragma("unroll") for (int nt = 0; nt < 4; ++nt) {                 \
                acc[mt][nt] = __builtin_amdgcn_mfma_f32_16x16x32_bf16(ah[mt], bh[nt], acc[mt][nt], 0, 0, 0); \
                acc[mt][nt] = __builtin_amdgcn_mfma_f32_16x16x32_bf16(ah[mt], bl[nt], acc[mt][nt], 0, 0, 0); \
                acc[mt][nt] = __builtin_amdgcn_mfma_f32_16x16x32_bf16(al[mt], bh[nt], acc[mt][nt], 0, 0, 0); \
            }                                                                  \
        __syncthreads();                                                       \
    }                                                                          \
    float bb[4];                                                               \
    _Pragma("unroll") for (int nt = 0; nt < 4; ++nt) {                         \
        const int col = n0 + wc*64 + nt*16 + l15;                              \
        bb[nt] = (bias) ? (bias)[col] : 0.0f;                                  \
    }                                                                          \
    float* zone = &fbuf[w*2112];                                               \
    const int s8 = lane >> 3;                                                  \
    const int c8 = (lane & 7) * 8;                                             \
    _Pragma("unroll") for (int p = 0; p < 2; ++p) {                            \
        _Pragma("unroll") for (int mt2 = 0; mt2 < 2; ++mt2) {                  \
            const int mt = 2*p + mt2;                                          \
            _Pragma("unroll") for (int nt = 0; nt < 4; ++nt)                   \
                _Pragma("unroll") for (int r = 0; r < 4; ++r)                  \
                    zone[(mt2*16 + qd*4 + r)*66 + nt*16 + l15] =               \
                        (alpha)*acc[mt][nt][r] + bb[nt];                       \
        }                                                                      \
        _Pragma("unroll") for (int u = 0; u < 4; ++u) {                        \
            const int rl = u*8 + s8;                                           \
            const float* src = &zone[rl*66 + c8];                              \
            float v8[8];                                                       \
            *(f32x2*)(v8)   = *(const f32x2*)(src);                            \
            *(f32x2*)(v8+2) = *(const f32x2*)(src+2);                          \
            *(f32x2*)(v8+4) = *(const f32x2*)(src+4);                          \
            *(f32x2*)(v8+6) = *(const f32x2*)(src+6);                          \
            s16x8 vh, vl;                                                      \
            _Pragma("unroll") for (int j = 0; j < 8; ++j) {                    \
                const u16 h = f2bf(v8[j]);                                     \
                vh[j] = (short)h;                                              \
                vl[j] = (short)f2bf(v8[j] - bf2f(h));                          \
            }                                                                  \
            const size_t o = (size_t)(m0 + wr*64 + p*32 + rl)*NU + (n0 + wc*64 + c8); \
            *(s16x8*)&(Ch)[o] = vh;                                            \
            *(s16x8*)&(Cl)[o] = vl;                                            \
        }                                                                      \
    }

// ---------------------------------------------------------------------------
// Single GEMM (r10-proven): 128x128 tile, grid (256,2).
// ---------------------------------------------------------------------------
__global__ __launch_bounds__(256, 2) void gemm_mfma(
    const u16* __restrict__ Ah, const u16* __restrict__ Al,
    const u16* __restrict__ Bh, const u16* __restrict__ Bl,
    u16* __restrict__ Ch, u16* __restrict__ Cl,
    const float* __restrict__ bias, const float alpha)
{
    __shared__ __align__(16) u16 lAh[128*32], lAl[128*32], lBh[128*32], lBl[128*32];
    __shared__ __align__(16) float fbuf[4*2112];
    GEMM_BODY(Ah, Al, Bh, Bl, Ch, Cl, bias, alpha, blockIdx.x, blockIdx.y)
}

// ---------------------------------------------------------------------------
// Pair GEMM: grid (256,2,2). z=0: C1 = -A1@B1 ; z=1: C2 = A2@B2 + bias2.
// Same body; wave-uniform pointer select at top. The two halves are
// data-independent (4 distinct plane slots).
// ---------------------------------------------------------------------------
__global__ __launch_bounds__(256, 2) void gemm_pair(
    const u16* __restrict__ A1h, const u16* __restrict__ A1l,
    const u16* __restrict__ B1h, const u16* __restrict__ B1l,
    u16* __restrict__ C1h, u16* __restrict__ C1l,
    const u16* __restrict__ A2h, const u16* __restrict__ A2l,
    const u16* __restrict__ B2h, const u16* __restrict__ B2l,
    u16* __restrict__ C2h, u16* __restrict__ C2l,
    const float* __restrict__ bias2)
{
    __shared__ __align__(16) u16 lAh[128*32], lAl[128*32], lBh[128*32], lBl[128*32];
    __shared__ __align__(16) float fbuf[4*2112];
    const int pr = blockIdx.z;
    const u16* Ah = pr ? A2h : A1h;  const u16* Al = pr ? A2l : A1l;
    const u16* Bh = pr ? B2h : B1h;  const u16* Bl = pr ? B2l : B1l;
    u16* Ch = pr ? C2h : C1h;        u16* Cl = pr ? C2l : C1l;
    const float* bias = pr ? bias2 : nullptr;
    const float alpha = pr ? 1.0f : -1.0f;
    GEMM_BODY(Ah, Al, Bh, Bl, Ch, Cl, bias, alpha, blockIdx.x, blockIdx.y)
}

// ---------------------------------------------------------------------------
// out = V0 @ W_out + b_out, N=10. One wave per batch row; V0 from planes.
// ---------------------------------------------------------------------------
__global__ __launch_bounds__(256) void out_gemm(
    const u16* __restrict__ V0h, const u16* __restrict__ V0l,
    const float* __restrict__ Wout,
    const float* __restrict__ bout, float* __restrict__ out)
{
    __shared__ float Ws[NU*NDOUT];
    const int t = threadIdx.x;
    for (int i = t; i < NU*NDOUT; i += 256) Ws[i] = Wout[i];
    __syncthreads();
    const int lane = t & 63;
    const int wv = t >> 6;
    const int row = blockIdx.x*4 + wv;
    float acc[NDOUT];
#pragma unroll
    for (int j = 0; j < NDOUT; ++j) acc[j] = 0.0f;
#pragma unroll
    for (int s = 0; s < 4; ++s) {
        const int k = lane + 64*s;
        const size_t o = (size_t)row*NU + k;
        const float v = bf2f(V0h[o]) + bf2f(V0l[o]);
#pragma unroll
        for (int j = 0; j < NDOUT; ++j) acc[j] = fmaf(v, Ws[k*NDOUT + j], acc[j]);
    }
#pragma unroll
    for (int off = 32; off > 0; off >>= 1) {
#pragma unroll
        for (int j = 0; j < NDOUT; ++j) acc[j] += __shfl_down(acc[j], off);
    }
    if (lane == 0) {
#pragma unroll
        for (int j = 0; j < NDOUT; ++j) out[(size_t)row*NDOUT + j] = acc[j] + bout[j];
    }
}

extern "C" void kernel_launch(void* const* d_in, const int* in_sizes, int n_in,
                              void* d_out, int out_size, void* d_ws, size_t ws_size,
                              hipStream_t stream)
{
    const float* x    = (const float*)d_in[0];
    const float* Win  = (const float*)d_in[1];
    const float* bin  = (const float*)d_in[2];
    const float* B0   = (const float*)d_in[3];
    const float* q    = (const float*)d_in[4];
    const float* Wout = (const float*)d_in[5];
    const float* bout = (const float*)d_in[6];
    float* out = (float*)d_out;

    // workspace carve
    u16* wnnh = (u16*)d_ws;
    u16* wnnl = wnnh + (size_t)NLAYERS*NUSQ;
    u16* wnth = wnnl + (size_t)NLAYERS*NUSQ;
    u16* wntl = wnth + (size_t)NLAYERS*NUSQ;
    float* bq = (float*)(wntl + (size_t)NLAYERS*NUSQ);
    u16* pl   = (u16*)(bq + NLAYERS*NU);
    const size_t PSZ = (size_t)NBATCH*NU;

    // plane slots (h,l per slot). 3 slots (~104 MB) always assumed; 4th slot
    // (~137 MB total) enables pair-fused dispatches.
    u16* sh[4]; u16* sl[4];
    for (int s = 0; s < 4; ++s) { sh[s] = pl + (size_t)(2*s)*PSZ; sl[s] = pl + (size_t)(2*s+1)*PSZ; }
    const size_t base_bytes = (size_t)((char*)pl - (char*)d_ws);
    const bool has4 = ws_size >= base_bytes + 8*PSZ*sizeof(u16);

    // fused: 6 invert blocks + 512 in_gemm blocks, concurrent
    fused_inv_ingemm<<<NLAYERS + 512, 512, 0, stream>>>(
        B0, q, wnnh, wnnl, wnth, wntl, bq,
        x, Win, bin, sh[0], sl[0], sh[1], sl[1]);

    const dim3 ggrid(NBATCH/128, NU/128);      // 256 x 2
    const dim3 pgrid(NBATCH/128, NU/128, 2);   // 256 x 2 x 2

    if (has4) {
        int iv0 = 0, iv1 = 1, f0 = 2, f1 = 3;
        for (int l = 0; l < NLAYERS - 1; ++l) {
            const size_t wo = (size_t)l*NUSQ;
            gemm_pair<<<pgrid, 256, 0, stream>>>(
                sh[iv1], sl[iv1], wnnh + wo, wnnl + wo, sh[f0], sl[f0],   // newV0 = -V1 @ M
                sh[iv0], sl[iv0], wnth + wo, wntl + wo, sh[f1], sl[f1],   // newV1 = V0 @ M^T + bq
                bq + (size_t)l*NU);
            const int t0 = iv0, t1 = iv1;
            iv0 = f0; iv1 = f1; f0 = t0; f1 = t1;
        }
        // layer 5: only newV0 is needed by the output
        const size_t wo = (size_t)(NLAYERS - 1)*NUSQ;
        gemm_mfma<<<ggrid, 256, 0, stream>>>(sh[iv1], sl[iv1], wnnh + wo, wnnl + wo,
                                             sh[f0], sl[f0], nullptr, -1.0f);
        out_gemm<<<NBATCH/4, 256, 0, stream>>>(sh[f0], sl[f0], Wout, bout, out);
    } else {
        u16 *v0h = sh[0], *v0l = sl[0], *v1h = sh[1], *v1l = sl[1], *frh = sh[2], *frl = sl[2];
        for (int l = 0; l < NLAYERS; ++l) {
            const size_t wo = (size_t)l*NUSQ;
            gemm_mfma<<<ggrid, 256, 0, stream>>>(v1h, v1l, wnnh + wo, wnnl + wo,
                                                 frh, frl, nullptr, -1.0f);
            if (l < NLAYERS - 1)   // layer 5's newV1 is dead
                gemm_mfma<<<ggrid, 256, 0, stream>>>(v0h, v0l, wnth + wo, wntl + wo,
                                                     v1h, v1l, bq + (size_t)l*NU, 1.0f);
            u16* t0 = v0h; u16* t1 = v0l;
            v0h = frh; v0l = frl; frh = t0; frl = t1;
        }
        out_gemm<<<NBATCH/4, 256, 0, stream>>>(v0h, v0l, Wout, bout, out);
    }
}